// Round 17
// baseline (253.397 us; speedup 1.0000x reference)
//
#include <hip/hip_runtime.h>
#include <cstdint>
#include <cstddef>

#define NN 100000
#define NE 1600000
#define NH 8
#define NC 40
#define NBKT 391            // ceil(NN / 256)
#define CHUNK 4096
#define P2BLKS ((NE + CHUNK - 1) / CHUNK)
#define G1BLKS 1563         // gemm1 blocks
#define BCBLKS 256          // bucketcnt blocks fused after gemm1

typedef _Float16 f16;
typedef f16 f16x2 __attribute__((ext_vector_type(2)));
typedef f16 f16x4 __attribute__((ext_vector_type(4)));
typedef f16 f16x8 __attribute__((ext_vector_type(8)));
typedef float f32x4 __attribute__((ext_vector_type(4)));

static __device__ __forceinline__ float leaky02(float x) {
  return x >= 0.f ? x : 0.2f * x;
}

static __device__ __forceinline__ int edge_at(const void* p, int is32, int i) {
  return is32 ? ((const int*)p)[i] : (int)((const long long*)p)[i];
}

// ---- prep (4 blocks): b0 W2p pack, b1 w1b2, b2 detect(+flag), b3 zero gbucket
__global__ __launch_bounds__(256) void prepdet_kernel(
    const float* __restrict__ W1, const float* __restrict__ att_src,
    const float* __restrict__ att_dst, const float* __restrict__ W2,
    const float* __restrict__ as2v, const float* __restrict__ ad2v,
    const int* __restrict__ esrc32, f16* __restrict__ W2p,
    float* __restrict__ w1b2, int* __restrict__ flag,
    int* __restrict__ gbucket) {
  __shared__ int lflag;
  if (blockIdx.x == 0) {
    for (int i = threadIdx.x; i < 8192; i += 256) {
      const int e = i & 7, lane = (i >> 3) & 63, t = (i >> 9) & 3, s = (i >> 11) & 3;
      const int k = 32 * s + ((lane >> 4) << 3) + e;
      const int c = 16 * t + (lane & 15);
      float v = 0.f;
      if (c < 40) {
        v = W2[k * 40 + c];
      } else if (c == 40 || c == 41) {
        const float* a = (c == 40) ? as2v : ad2v;
        float sacc = 0.f;
#pragma unroll 8
        for (int j = 0; j < 40; ++j) sacc += W2[k * 40 + j] * a[j];
        v = sacc;
      }
      W2p[i] = (f16)v;
    }
  } else if (blockIdx.x == 1) {
    const int k = threadIdx.x;
    if (k < 128) {
#pragma unroll
      for (int col = 0; col < 16; ++col) {
        const int h = col & 7;
        const float* av = (col < 8) ? att_src : att_dst;
        float v = 0.f;
#pragma unroll
        for (int f = 0; f < 16; ++f)
          v += W1[k * 128 + h * 16 + f] * av[h * 16 + f];
        w1b2[k * 16 + col] = v;
      }
    }
  } else if (blockIdx.x == 2) {
    if (threadIdx.x == 0) lflag = 0;
    __syncthreads();
    for (int i = threadIdx.x; i < 1024; i += 256)
      if (esrc32[2 * i + 1] != 0) atomicOr(&lflag, 1);
    __syncthreads();
    if (threadIdx.x == 0) *flag = lflag;
  } else {
    for (int i = threadIdx.x; i < NBKT; i += 256) gbucket[i] = 0;
  }
}

// ------- fused: gemm1 (MFMA, blocks <G1BLKS) + bucketcnt (blocks >=G1BLKS) --
__global__ __launch_bounds__(256) void g1bc_kernel(
    const float* __restrict__ x, const float* __restrict__ W1,
    const float* __restrict__ w1b2, f16* __restrict__ h1,
    float* __restrict__ as1, float* __restrict__ ad1,
    const void* __restrict__ edst, const int* __restrict__ flag,
    int* __restrict__ gbucket) {
  __shared__ f16 wp[16384];    // [kt][ct][lane][e]
  __shared__ f16 wp2[2048];    // [kt][lane][e]
  __shared__ int hcnt[NBKT];
  const int t = threadIdx.x;
  if (blockIdx.x >= G1BLKS) {
    for (int i = t; i < NBKT; i += 256) hcnt[i] = 0;
    __syncthreads();
    const int is32 = *flag;
    const int bid = blockIdx.x - G1BLKS;
    int i = bid * 256 + t;
    const int st = BCBLKS * 256;
    for (; i < NE; i += st) atomicAdd(&hcnt[edge_at(edst, is32, i) >> 8], 1);
    __syncthreads();
    for (int b = t; b < NBKT; b += 256)
      if (hcnt[b]) atomicAdd(&gbucket[b], hcnt[b]);
    return;
  }
  // ---- gemm1 part ----
  for (int i = t; i < 16384; i += 256) {
    const int e = i & 7, ln = (i >> 3) & 63, ct = (i >> 9) & 7, kt = i >> 12;
    const int k = kt * 32 + ((ln >> 4) << 3) + e;
    const int c = ct * 16 + (ln & 15);
    wp[i] = (f16)W1[k * 128 + c];
  }
  for (int i = t; i < 2048; i += 256) {
    const int e = i & 7, ln = (i >> 3) & 63, kt = i >> 9;
    const int k = kt * 32 + ((ln >> 4) << 3) + e;
    const int col = ln & 15;
    wp2[i] = (f16)w1b2[k * 16 + col];
  }
  __syncthreads();
  const int lane = t & 63;
  const int rsub = lane & 15, kg = lane >> 4;
  const int wid = (blockIdx.x * 256 + t) >> 6;
  if (wid >= NN / 16) return;
  const int row0 = wid * 16;
  const float* ap = x + (size_t)(row0 + rsub) * 128 + kg * 8;
  f16x8 a[4];
#pragma unroll
  for (int kt = 0; kt < 4; ++kt) {
    float4 v0 = *(const float4*)(ap + kt * 32);
    float4 v1 = *(const float4*)(ap + kt * 32 + 4);
    f16x8 av = { (f16)v0.x, (f16)v0.y, (f16)v0.z, (f16)v0.w,
                 (f16)v1.x, (f16)v1.y, (f16)v1.z, (f16)v1.w };
    a[kt] = av;
  }
  const f16x8* bp = (const f16x8*)wp;
  const f16x8* bp2 = (const f16x8*)wp2;
  const f32x4 z4 = { 0.f, 0.f, 0.f, 0.f };
  f32x4 acc[8];
#pragma unroll
  for (int ct = 0; ct < 8; ++ct) acc[ct] = z4;
  f32x4 acc2 = z4;
#pragma unroll
  for (int kt = 0; kt < 4; ++kt) {
#pragma unroll
    for (int ct = 0; ct < 8; ++ct)
      acc[ct] = __builtin_amdgcn_mfma_f32_16x16x32_f16(
          a[kt], bp[(kt * 8 + ct) * 64 + lane], acc[ct], 0, 0, 0);
    acc2 = __builtin_amdgcn_mfma_f32_16x16x32_f16(
        a[kt], bp2[kt * 64 + lane], acc2, 0, 0, 0);
  }
  const int r0 = row0 + kg * 4;
#pragma unroll
  for (int ct = 0; ct < 8; ++ct) {
#pragma unroll
    for (int r = 0; r < 4; ++r)
      h1[(size_t)(r0 + r) * 128 + ct * 16 + rsub] = (f16)acc[ct][r];
  }
#pragma unroll
  for (int r = 0; r < 4; ++r) {
    if (rsub < 8) as1[(r0 + r) * 8 + rsub] = acc2[r];
    else          ad1[(r0 + r) * 8 + rsub - 8] = acc2[r];
  }
}

// ---------------- CSR build: scan -> partition -> build ----------------
__global__ __launch_bounds__(512) void bucketscan_kernel(
    const int* __restrict__ gbucket, int* __restrict__ bb,
    int* __restrict__ bcur) {
  __shared__ int wsum[8];
  const int t = threadIdx.x;
  const int lane = t & 63, w = t >> 6;
  int v = (t < NBKT) ? gbucket[t] : 0;
  int sc = v;
#pragma unroll
  for (int off = 1; off < 64; off <<= 1) {
    int o = __shfl_up(sc, off);
    if (lane >= off) sc += o;
  }
  if (lane == 63) wsum[w] = sc;
  __syncthreads();
  if (t < 8) {
    int ws = wsum[t];
#pragma unroll
    for (int off = 1; off < 8; off <<= 1) {
      int o = __shfl_up(ws, off);
      if (t >= off) ws += o;
    }
    wsum[t] = ws;
  }
  __syncthreads();
  if (w > 0) sc += wsum[w - 1];
  if (t < NBKT) {
    int ex = sc - v;
    bb[t] = ex;
    bcur[t] = ex;
  }
  if (t == NBKT - 1) bb[NBKT] = sc;   // == NE
}

__global__ __launch_bounds__(256) void partition_kernel(
    const void* __restrict__ src, const void* __restrict__ dst,
    const int* __restrict__ flag, int* __restrict__ bcur,
    unsigned int* __restrict__ bucketbuf) {
  __shared__ int h[NBKT];
  __shared__ int gb[NBKT];
  const int t = threadIdx.x;
  const int is32 = *flag;
  const int lo = blockIdx.x * CHUNK;
  const int hi = min(lo + CHUNK, NE);
  for (int i = t; i < NBKT; i += 256) h[i] = 0;
  __syncthreads();
  for (int i = lo + t; i < hi; i += 256)
    atomicAdd(&h[edge_at(dst, is32, i) >> 8], 1);
  __syncthreads();
  for (int b = t; b < NBKT; b += 256)
    gb[b] = h[b] ? atomicAdd(&bcur[b], h[b]) : 0;
  __syncthreads();
  for (int i = t; i < NBKT; i += 256) h[i] = 0;   // reuse as local cursor
  __syncthreads();
  for (int i = lo + t; i < hi; i += 256) {
    int d = edge_at(dst, is32, i);
    int b = d >> 8;
    int s = atomicAdd(&h[b], 1);
    bucketbuf[gb[b] + s] =
        ((unsigned)(d & 255) << 17) | (unsigned)edge_at(src, is32, i);
  }
}

__global__ __launch_bounds__(256) void build_kernel(
    const unsigned int* __restrict__ bucketbuf, const int* __restrict__ bb,
    int* __restrict__ rowptr, int* __restrict__ csr) {
  __shared__ int cnt[256];
  __shared__ int cur[256];
  __shared__ int wsum[4];
  const int k = blockIdx.x;
  const int t = threadIdx.x;
  const int node0 = k << 8;
  const int lo = bb[k], hi = bb[k + 1];
  cnt[t] = 0;
  __syncthreads();
  for (int i = lo + t; i < hi; i += 256)
    atomicAdd(&cnt[bucketbuf[i] >> 17], 1);
  __syncthreads();
  const int lane = t & 63, w = t >> 6;
  const int v = cnt[t];
  int sc = v;
#pragma unroll
  for (int off = 1; off < 64; off <<= 1) {
    int o = __shfl_up(sc, off);
    if (lane >= off) sc += o;
  }
  if (lane == 63) wsum[w] = sc;
  __syncthreads();
  if (t < 4) {
    int ws = wsum[t];
#pragma unroll
    for (int off = 1; off < 4; off <<= 1) {
      int o = __shfl_up(ws, off);
      if (t >= off) ws += o;
    }
    wsum[t] = ws;
  }
  __syncthreads();
  if (w > 0) sc += wsum[w - 1];
  const int ex = lo + sc - v;
  const int node = node0 + t;
  if (node < NN) rowptr[node] = ex;
  if (node == NN - 1) rowptr[NN] = NE;
  cur[t] = ex;
  __syncthreads();
  for (int i = lo + t; i < hi; i += 256) {
    unsigned e = bucketbuf[i];
    int pos = atomicAdd(&cur[e >> 17], 1);
    csr[pos] = (int)(e & 0x1FFFF);
  }
}

// --- fused layer-1 aggregate + softmax + ELU + layer-2 MFMA projection ---
// wave-private: each wave owns 4 nodes + a 1KB LDS tile (padded stride 136);
// NO __syncthreads — same-wave LDS RAW ordered by lgkmcnt. Epilogue: A-frag
// rows 0-3 = the wave's nodes (rows 4-15 garbage, not stored), 3 ct-tiles.
__global__ __launch_bounds__(256) void agg1g2_kernel(
    const f16* __restrict__ h1, const float* __restrict__ as1,
    const float* __restrict__ ad1, const int* __restrict__ rowptr,
    const int* __restrict__ csr, const f16* __restrict__ W2p,
    f16* __restrict__ h2, float* __restrict__ as2, float* __restrict__ ad2) {
  __shared__ f16 g1s[4][4 * 136];   // [wave][row*136 + feat]
  const int t = threadIdx.x;
  const int lane = t & 63;
  const int w = t >> 6;
  f16* g1w = &g1s[w][0];
  const int j = lane >> 3, hd = lane & 7;
  const int q = lane >> 4;          // PV edge sub-slot (0..3)
  const int part = lane & 15;       // 8-feature block
  const int base_node = (blockIdx.x * 4 + w) * 4;
  for (int ii = 0; ii < 4; ++ii) {
    const int wid = base_node + ii;
    const int lo = rowptr[wid], hi = rowptr[wid + 1];
    const int deg = hi - lo;
    const float advv = ad1[wid * 8 + hd];
    float lk0 = -3.4e38f, lk1 = -3.4e38f, lk2 = -3.4e38f, lk3 = -3.4e38f;
    int s0 = 0, s1 = 0, s2 = 0, s3 = 0;
    if (j < deg)      { s0 = csr[lo + j];      lk0 = leaky02(as1[(size_t)s0 * 8 + hd] + advv); }
    if (8 + j < deg)  { s1 = csr[lo + 8 + j];  lk1 = leaky02(as1[(size_t)s1 * 8 + hd] + advv); }
    if (16 + j < deg) { s2 = csr[lo + 16 + j]; lk2 = leaky02(as1[(size_t)s2 * 8 + hd] + advv); }
    if (24 + j < deg) { s3 = csr[lo + 24 + j]; lk3 = leaky02(as1[(size_t)s3 * 8 + hd] + advv); }
    float m = fmaxf(fmaxf(lk0, lk1), fmaxf(lk2, lk3));
    for (int base = 32; base < deg; base += 8) {   // rare tail
      int e = base + j;
      float xv = (e < deg) ? leaky02(as1[(size_t)csr[lo + e] * 8 + hd] + advv)
                           : -3.4e38f;
      m = fmaxf(m, xv);
    }
    m = fmaxf(m, __shfl_xor(m, 8));
    m = fmaxf(m, __shfl_xor(m, 16));
    m = fmaxf(m, __shfl_xor(m, 32));
    float sum = 0.f;
    float acc[8];
#pragma unroll
    for (int i = 0; i < 8; ++i) acc[i] = 0.f;
    for (int base = 0; base < deg; base += 8) {
      int e = base + j;
      float p = 0.f;
      int s = 0;
      if (base == 0)       { s = s0; if (e < deg) p = __expf(lk0 - m); }
      else if (base == 8)  { s = s1; if (e < deg) p = __expf(lk1 - m); }
      else if (base == 16) { s = s2; if (e < deg) p = __expf(lk2 - m); }
      else if (base == 24) { s = s3; if (e < deg) p = __expf(lk3 - m); }
      else if (e < deg) {
        s = csr[lo + e];
        p = __expf(leaky02(as1[(size_t)s * 8 + hd] + advv) - m);
      }
      sum += p;
      int sja = __shfl(s, q * 8);
      float pja = __shfl(p, q * 8 + (part >> 1));
      int sjb = __shfl(s, (4 + q) * 8);
      float pjb = __shfl(p, (4 + q) * 8 + (part >> 1));
      f16x8 hva = *(const f16x8*)(h1 + (size_t)sja * 128 + part * 8);
      f16x8 hvb = *(const f16x8*)(h1 + (size_t)sjb * 128 + part * 8);
#pragma unroll
      for (int i = 0; i < 8; ++i) acc[i] += pja * (float)hva[i];
#pragma unroll
      for (int i = 0; i < 8; ++i) acc[i] += pjb * (float)hvb[i];
    }
    sum += __shfl_xor(sum, 8);
    sum += __shfl_xor(sum, 16);
    sum += __shfl_xor(sum, 32);
#pragma unroll
    for (int i = 0; i < 8; ++i) {
      acc[i] += __shfl_xor(acc[i], 16);
      acc[i] += __shfl_xor(acc[i], 32);
    }
    float sden = __shfl(sum, part >> 1);
    float inv = 1.f / fmaxf(sden, 1e-16f);
    if (lane < 16) {
      f16x8 ov;
#pragma unroll
      for (int i = 0; i < 8; ++i) {
        float v = acc[i] * inv;
        v = v > 0.f ? v : (__expf(v) - 1.f);
        ov[i] = (f16)v;
      }
      *(f16x8*)&g1w[ii * 136 + part * 8] = ov;
    }
  }
  // ---- wave-private gemm2 epilogue (no barrier: same-wave LDS RAW) ----
  const int rsub = lane & 15, kg = lane >> 4;
  const int arow = rsub & 3;        // rows 4-15 read garbage, never stored
  f16x8 a0 = *(const f16x8*)&g1w[arow * 136 + 0 * 32 + kg * 8];
  f16x8 a1 = *(const f16x8*)&g1w[arow * 136 + 1 * 32 + kg * 8];
  f16x8 a2 = *(const f16x8*)&g1w[arow * 136 + 2 * 32 + kg * 8];
  f16x8 a3 = *(const f16x8*)&g1w[arow * 136 + 3 * 32 + kg * 8];
  const f16x8* bp = (const f16x8*)W2p;
  const f32x4 z4 = { 0.f, 0.f, 0.f, 0.f };
  f32x4 acc2[3];
#pragma unroll
  for (int ct = 0; ct < 3; ++ct) {
    acc2[ct] = z4;
    acc2[ct] = __builtin_amdgcn_mfma_f32_16x16x32_f16(a0, bp[(0 * 4 + ct) * 64 + lane], acc2[ct], 0, 0, 0);
    acc2[ct] = __builtin_amdgcn_mfma_f32_16x16x32_f16(a1, bp[(1 * 4 + ct) * 64 + lane], acc2[ct], 0, 0, 0);
    acc2[ct] = __builtin_amdgcn_mfma_f32_16x16x32_f16(a2, bp[(2 * 4 + ct) * 64 + lane], acc2[ct], 0, 0, 0);
    acc2[ct] = __builtin_amdgcn_mfma_f32_16x16x32_f16(a3, bp[(3 * 4 + ct) * 64 + lane], acc2[ct], 0, 0, 0);
  }
  // D: col = ct*16 + rsub, row = kg*4 + r; only kg==0 rows (0-3) are valid.
  if (kg == 0) {
#pragma unroll
    for (int ct = 0; ct < 3; ++ct) {
      const int col = ct * 16 + rsub;
      if (col < 40) {
#pragma unroll
        for (int r = 0; r < 4; ++r)
          h2[(size_t)(base_node + r) * 40 + col] = (f16)acc2[ct][r];
      }
    }
    if (rsub == 8) {          // col 40: src logits
#pragma unroll
      for (int r = 0; r < 4; ++r) as2[base_node + r] = acc2[2][r];
    } else if (rsub == 9) {   // col 41: dst logits
#pragma unroll
      for (int r = 0; r < 4; ++r) ad2[base_node + r] = acc2[2][r];
    }
  }
}

// ---------------- layer-2 aggregate + softmax -> d_out ----------------
__global__ __launch_bounds__(256) void agg2_kernel(
    const f16* __restrict__ h2, const float* __restrict__ as2,
    const float* __restrict__ ad2, const int* __restrict__ rowptr,
    const int* __restrict__ csr, const float* __restrict__ b2,
    float* __restrict__ out) {
  const int wid = (blockIdx.x * 256 + threadIdx.x) >> 6;
  const int lane = threadIdx.x & 63;
  if (wid >= NN) return;
  const int lo = rowptr[wid], hi = rowptr[wid + 1];
  const int deg = hi - lo;
  const float advv = ad2[wid];
  float lkc = -3.4e38f;
  int sc = 0;
  if (lane < deg) {
    sc = csr[lo + lane];
    lkc = leaky02(as2[sc] + advv);
  }
  float m = lkc;
  for (int base = 64; base < deg; base += 64) {   // rare tail
    int e = base + lane;
    float xv = (e < deg) ? leaky02(as2[csr[lo + e]] + advv) : -3.4e38f;
    m = fmaxf(m, xv);
  }
#pragma unroll
  for (int off = 32; off >= 1; off >>= 1) m = fmaxf(m, __shfl_xor(m, off));
  const int j8 = lane >> 3, part8 = lane & 7;
  const bool pvon = part8 < 5;
  float sum = 0.f;
  float acc[8];
#pragma unroll
  for (int i = 0; i < 8; ++i) acc[i] = 0.f;
  for (int base = 0; base < deg; base += 64) {
    int e = base + lane;
    float p = 0.f;
    int s = 0;
    if (base == 0) {
      s = sc;
      if (lane < deg) p = __expf(lkc - m);
    } else if (e < deg) {
      s = csr[lo + e];
      p = __expf(leaky02(as2[s] + advv) - m);
    }
    sum += p;
    const int ng = (min(64, deg - base) + 7) >> 3;
    int g = 0;
    for (; g + 1 < ng; g += 2) {
      int sl1 = g * 8 + j8, sl2 = (g + 1) * 8 + j8;
      int sj1 = __shfl(s, sl1);
      float pj1 = __shfl(p, sl1);
      int sj2 = __shfl(s, sl2);
      float pj2 = __shfl(p, sl2);
      if (pvon) {
        f16x8 hv1 = *(const f16x8*)(h2 + (size_t)sj1 * 40 + part8 * 8);
        f16x8 hv2 = *(const f16x8*)(h2 + (size_t)sj2 * 40 + part8 * 8);
#pragma unroll
        for (int i = 0; i < 8; ++i) acc[i] += pj1 * (float)hv1[i];
#pragma unroll
        for (int i = 0; i < 8; ++i) acc[i] += pj2 * (float)hv2[i];
      }
    }
    if (g < ng) {
      int sl = g * 8 + j8;
      int sj = __shfl(s, sl);
      float pj = __shfl(p, sl);
      if (pvon) {
        f16x8 hv = *(const f16x8*)(h2 + (size_t)sj * 40 + part8 * 8);
#pragma unroll
        for (int i = 0; i < 8; ++i) acc[i] += pj * (float)hv[i];
      }
    }
  }
#pragma unroll
  for (int off = 32; off >= 1; off >>= 1) sum += __shfl_xor(sum, off);
#pragma unroll
  for (int i = 0; i < 8; ++i) {
    acc[i] += __shfl_xor(acc[i], 8);
    acc[i] += __shfl_xor(acc[i], 16);
    acc[i] += __shfl_xor(acc[i], 32);
  }
  const float inv = 1.f / fmaxf(sum, 1e-16f);
  if (lane < 5) {   // j8 == 0, part8 == lane -> cols lane*8 .. lane*8+7
    float4 b0 = *(const float4*)(b2 + lane * 8);
    float4 b1 = *(const float4*)(b2 + lane * 8 + 4);
    float4 v0 = { acc[0] * inv + b0.x, acc[1] * inv + b0.y,
                  acc[2] * inv + b0.z, acc[3] * inv + b0.w };
    float4 v1 = { acc[4] * inv + b1.x, acc[5] * inv + b1.y,
                  acc[6] * inv + b1.z, acc[7] * inv + b1.w };
    *(float4*)(out + (size_t)wid * 40 + lane * 8) = v0;
    *(float4*)(out + (size_t)wid * 40 + lane * 8 + 4) = v1;
  }
}

extern "C" void kernel_launch(void* const* d_in, const int* in_sizes, int n_in,
                              void* d_out, int out_size, void* d_ws, size_t ws_size,
                              hipStream_t stream) {
  (void)in_sizes; (void)n_in; (void)out_size; (void)ws_size;
  const float* x = (const float*)d_in[0];
  const void* esrc = d_in[1];
  const void* edst = d_in[2];
  const float* W1 = (const float*)d_in[3];
  const float* att_s1 = (const float*)d_in[4];
  const float* att_d1 = (const float*)d_in[5];
  const float* W2 = (const float*)d_in[7];
  const float* att_s2 = (const float*)d_in[8];
  const float* att_d2 = (const float*)d_in[9];
  const float* b2 = (const float*)d_in[10];

  char* p = (char*)d_ws;
  auto alloc = [&](size_t bytes) {
    char* q = p;
    p += (bytes + 255) & ~(size_t)255;
    return q;
  };
  f16* h1 = (f16*)alloc((size_t)NN * 128 * 2);
  f16* h2 = (f16*)alloc((size_t)NN * 40 * 2);
  float* as1 = (float*)alloc((size_t)NN * 8 * 4);
  float* ad1 = (float*)alloc((size_t)NN * 8 * 4);
  float* as2 = (float*)alloc((size_t)NN * 4);
  float* ad2 = (float*)alloc((size_t)NN * 4);
  f16* W2p = (f16*)alloc((size_t)8192 * 2);
  float* w1b2 = (float*)alloc((size_t)128 * 16 * 4);
  int* rowptr = (int*)alloc((size_t)(NN + 1) * 4);
  int* csr = (int*)alloc((size_t)NE * 4);
  unsigned int* bucketbuf = (unsigned int*)alloc((size_t)NE * 4);
  int* gbucket = (int*)alloc((size_t)NBKT * 4);
  int* bb = (int*)alloc((size_t)(NBKT + 1) * 4);
  int* bcur = (int*)alloc((size_t)NBKT * 4);
  int* flag = (int*)alloc(256);

  prepdet_kernel<<<4, 256, 0, stream>>>(W1, att_s1, att_d1, W2, att_s2,
                                        att_d2, (const int*)esrc, W2p, w1b2,
                                        flag, gbucket);
  g1bc_kernel<<<G1BLKS + BCBLKS, 256, 0, stream>>>(x, W1, w1b2, h1, as1, ad1,
                                                   edst, flag, gbucket);
  bucketscan_kernel<<<1, 512, 0, stream>>>(gbucket, bb, bcur);
  partition_kernel<<<P2BLKS, 256, 0, stream>>>(esrc, edst, flag, bcur, bucketbuf);
  build_kernel<<<NBKT, 256, 0, stream>>>(bucketbuf, bb, rowptr, csr);
  agg1g2_kernel<<<6250, 256, 0, stream>>>(h1, as1, ad1, rowptr, csr, W2p,
                                          h2, as2, ad2);
  agg2_kernel<<<25000, 256, 0, stream>>>(h2, as2, ad2, rowptr, csr, b2,
                                         (float*)d_out);
}

// Round 18
// 244.167 us; speedup vs baseline: 1.0378x; 1.0378x over previous
//
#include <hip/hip_runtime.h>
#include <cstdint>
#include <cstddef>

#define NN 100000
#define NE 1600000
#define NH 8
#define NC 40
#define NBKT 391            // ceil(NN / 256)
#define CHUNK 4096
#define P2BLKS ((NE + CHUNK - 1) / CHUNK)
#define G1BLKS 1563         // gemm1 blocks
#define BCBLKS 256          // bucketcnt blocks fused after gemm1

typedef _Float16 f16;
typedef f16 f16x2 __attribute__((ext_vector_type(2)));
typedef f16 f16x4 __attribute__((ext_vector_type(4)));
typedef f16 f16x8 __attribute__((ext_vector_type(8)));
typedef float f32x4 __attribute__((ext_vector_type(4)));

static __device__ __forceinline__ float leaky02(float x) {
  return x >= 0.f ? x : 0.2f * x;
}

static __device__ __forceinline__ int edge_at(const void* p, int is32, int i) {
  return is32 ? ((const int*)p)[i] : (int)((const long long*)p)[i];
}

// ---- prep (4 blocks): b0 W2p pack, b1 w1b2, b2 detect(+flag), b3 zero gbucket
__global__ __launch_bounds__(256) void prepdet_kernel(
    const float* __restrict__ W1, const float* __restrict__ att_src,
    const float* __restrict__ att_dst, const float* __restrict__ W2,
    const float* __restrict__ as2v, const float* __restrict__ ad2v,
    const int* __restrict__ esrc32, f16* __restrict__ W2p,
    float* __restrict__ w1b2, int* __restrict__ flag,
    int* __restrict__ gbucket) {
  __shared__ int lflag;
  if (blockIdx.x == 0) {
    for (int i = threadIdx.x; i < 8192; i += 256) {
      const int e = i & 7, lane = (i >> 3) & 63, t = (i >> 9) & 3, s = (i >> 11) & 3;
      const int k = 32 * s + ((lane >> 4) << 3) + e;
      const int c = 16 * t + (lane & 15);
      float v = 0.f;
      if (c < 40) {
        v = W2[k * 40 + c];
      } else if (c == 40 || c == 41) {
        const float* a = (c == 40) ? as2v : ad2v;
        float sacc = 0.f;
#pragma unroll 8
        for (int j = 0; j < 40; ++j) sacc += W2[k * 40 + j] * a[j];
        v = sacc;
      }
      W2p[i] = (f16)v;
    }
  } else if (blockIdx.x == 1) {
    const int k = threadIdx.x;
    if (k < 128) {
#pragma unroll
      for (int col = 0; col < 16; ++col) {
        const int h = col & 7;
        const float* av = (col < 8) ? att_src : att_dst;
        float v = 0.f;
#pragma unroll
        for (int f = 0; f < 16; ++f)
          v += W1[k * 128 + h * 16 + f] * av[h * 16 + f];
        w1b2[k * 16 + col] = v;
      }
    }
  } else if (blockIdx.x == 2) {
    if (threadIdx.x == 0) lflag = 0;
    __syncthreads();
    for (int i = threadIdx.x; i < 1024; i += 256)
      if (esrc32[2 * i + 1] != 0) atomicOr(&lflag, 1);
    __syncthreads();
    if (threadIdx.x == 0) *flag = lflag;
  } else {
    for (int i = threadIdx.x; i < NBKT; i += 256) gbucket[i] = 0;
  }
}

// ------- fused: gemm1 (MFMA, blocks <G1BLKS) + bucketcnt (blocks >=G1BLKS) --
__global__ __launch_bounds__(256) void g1bc_kernel(
    const float* __restrict__ x, const float* __restrict__ W1,
    const float* __restrict__ w1b2, f16* __restrict__ h1,
    float* __restrict__ as1, float* __restrict__ ad1,
    const void* __restrict__ edst, const int* __restrict__ flag,
    int* __restrict__ gbucket) {
  __shared__ f16 wp[16384];    // [kt][ct][lane][e]
  __shared__ f16 wp2[2048];    // [kt][lane][e]
  __shared__ int hcnt[NBKT];
  const int t = threadIdx.x;
  if (blockIdx.x >= G1BLKS) {
    for (int i = t; i < NBKT; i += 256) hcnt[i] = 0;
    __syncthreads();
    const int is32 = *flag;
    const int bid = blockIdx.x - G1BLKS;
    int i = bid * 256 + t;
    const int st = BCBLKS * 256;
    for (; i < NE; i += st) atomicAdd(&hcnt[edge_at(edst, is32, i) >> 8], 1);
    __syncthreads();
    for (int b = t; b < NBKT; b += 256)
      if (hcnt[b]) atomicAdd(&gbucket[b], hcnt[b]);
    return;
  }
  // ---- gemm1 part ----
  for (int i = t; i < 16384; i += 256) {
    const int e = i & 7, ln = (i >> 3) & 63, ct = (i >> 9) & 7, kt = i >> 12;
    const int k = kt * 32 + ((ln >> 4) << 3) + e;
    const int c = ct * 16 + (ln & 15);
    wp[i] = (f16)W1[k * 128 + c];
  }
  for (int i = t; i < 2048; i += 256) {
    const int e = i & 7, ln = (i >> 3) & 63, kt = i >> 9;
    const int k = kt * 32 + ((ln >> 4) << 3) + e;
    const int col = ln & 15;
    wp2[i] = (f16)w1b2[k * 16 + col];
  }
  __syncthreads();
  const int lane = t & 63;
  const int rsub = lane & 15, kg = lane >> 4;
  const int wid = (blockIdx.x * 256 + t) >> 6;
  if (wid >= NN / 16) return;
  const int row0 = wid * 16;
  const float* ap = x + (size_t)(row0 + rsub) * 128 + kg * 8;
  f16x8 a[4];
#pragma unroll
  for (int kt = 0; kt < 4; ++kt) {
    float4 v0 = *(const float4*)(ap + kt * 32);
    float4 v1 = *(const float4*)(ap + kt * 32 + 4);
    f16x8 av = { (f16)v0.x, (f16)v0.y, (f16)v0.z, (f16)v0.w,
                 (f16)v1.x, (f16)v1.y, (f16)v1.z, (f16)v1.w };
    a[kt] = av;
  }
  const f16x8* bp = (const f16x8*)wp;
  const f16x8* bp2 = (const f16x8*)wp2;
  const f32x4 z4 = { 0.f, 0.f, 0.f, 0.f };
  f32x4 acc[8];
#pragma unroll
  for (int ct = 0; ct < 8; ++ct) acc[ct] = z4;
  f32x4 acc2 = z4;
#pragma unroll
  for (int kt = 0; kt < 4; ++kt) {
#pragma unroll
    for (int ct = 0; ct < 8; ++ct)
      acc[ct] = __builtin_amdgcn_mfma_f32_16x16x32_f16(
          a[kt], bp[(kt * 8 + ct) * 64 + lane], acc[ct], 0, 0, 0);
    acc2 = __builtin_amdgcn_mfma_f32_16x16x32_f16(
        a[kt], bp2[kt * 64 + lane], acc2, 0, 0, 0);
  }
  const int r0 = row0 + kg * 4;
#pragma unroll
  for (int ct = 0; ct < 8; ++ct) {
#pragma unroll
    for (int r = 0; r < 4; ++r)
      h1[(size_t)(r0 + r) * 128 + ct * 16 + rsub] = (f16)acc[ct][r];
  }
#pragma unroll
  for (int r = 0; r < 4; ++r) {
    if (rsub < 8) as1[(r0 + r) * 8 + rsub] = acc2[r];
    else          ad1[(r0 + r) * 8 + rsub - 8] = acc2[r];
  }
}

// ---------------- CSR build: scan -> partition -> build ----------------
__global__ __launch_bounds__(512) void bucketscan_kernel(
    const int* __restrict__ gbucket, int* __restrict__ bb,
    int* __restrict__ bcur) {
  __shared__ int wsum[8];
  const int t = threadIdx.x;
  const int lane = t & 63, w = t >> 6;
  int v = (t < NBKT) ? gbucket[t] : 0;
  int sc = v;
#pragma unroll
  for (int off = 1; off < 64; off <<= 1) {
    int o = __shfl_up(sc, off);
    if (lane >= off) sc += o;
  }
  if (lane == 63) wsum[w] = sc;
  __syncthreads();
  if (t < 8) {
    int ws = wsum[t];
#pragma unroll
    for (int off = 1; off < 8; off <<= 1) {
      int o = __shfl_up(ws, off);
      if (t >= off) ws += o;
    }
    wsum[t] = ws;
  }
  __syncthreads();
  if (w > 0) sc += wsum[w - 1];
  if (t < NBKT) {
    int ex = sc - v;
    bb[t] = ex;
    bcur[t] = ex;
  }
  if (t == NBKT - 1) bb[NBKT] = sc;   // == NE
}

__global__ __launch_bounds__(256) void partition_kernel(
    const void* __restrict__ src, const void* __restrict__ dst,
    const int* __restrict__ flag, int* __restrict__ bcur,
    unsigned int* __restrict__ bucketbuf) {
  __shared__ int h[NBKT];
  __shared__ int gb[NBKT];
  const int t = threadIdx.x;
  const int is32 = *flag;
  const int lo = blockIdx.x * CHUNK;
  const int hi = min(lo + CHUNK, NE);
  for (int i = t; i < NBKT; i += 256) h[i] = 0;
  __syncthreads();
  for (int i = lo + t; i < hi; i += 256)
    atomicAdd(&h[edge_at(dst, is32, i) >> 8], 1);
  __syncthreads();
  for (int b = t; b < NBKT; b += 256)
    gb[b] = h[b] ? atomicAdd(&bcur[b], h[b]) : 0;
  __syncthreads();
  for (int i = t; i < NBKT; i += 256) h[i] = 0;   // reuse as local cursor
  __syncthreads();
  for (int i = lo + t; i < hi; i += 256) {
    int d = edge_at(dst, is32, i);
    int b = d >> 8;
    int s = atomicAdd(&h[b], 1);
    bucketbuf[gb[b] + s] =
        ((unsigned)(d & 255) << 17) | (unsigned)edge_at(src, is32, i);
  }
}

__global__ __launch_bounds__(256) void build_kernel(
    const unsigned int* __restrict__ bucketbuf, const int* __restrict__ bb,
    int* __restrict__ rowptr, int* __restrict__ csr) {
  __shared__ int cnt[256];
  __shared__ int cur[256];
  __shared__ int wsum[4];
  const int k = blockIdx.x;
  const int t = threadIdx.x;
  const int node0 = k << 8;
  const int lo = bb[k], hi = bb[k + 1];
  cnt[t] = 0;
  __syncthreads();
  for (int i = lo + t; i < hi; i += 256)
    atomicAdd(&cnt[bucketbuf[i] >> 17], 1);
  __syncthreads();
  const int lane = t & 63, w = t >> 6;
  const int v = cnt[t];
  int sc = v;
#pragma unroll
  for (int off = 1; off < 64; off <<= 1) {
    int o = __shfl_up(sc, off);
    if (lane >= off) sc += o;
  }
  if (lane == 63) wsum[w] = sc;
  __syncthreads();
  if (t < 4) {
    int ws = wsum[t];
#pragma unroll
    for (int off = 1; off < 4; off <<= 1) {
      int o = __shfl_up(ws, off);
      if (t >= off) ws += o;
    }
    wsum[t] = ws;
  }
  __syncthreads();
  if (w > 0) sc += wsum[w - 1];
  const int ex = lo + sc - v;
  const int node = node0 + t;
  if (node < NN) rowptr[node] = ex;
  if (node == NN - 1) rowptr[NN] = NE;
  cur[t] = ex;
  __syncthreads();
  for (int i = lo + t; i < hi; i += 256) {
    unsigned e = bucketbuf[i];
    int pos = atomicAdd(&cur[e >> 17], 1);
    csr[pos] = (int)(e & 0x1FFFF);
  }
}

// --- fused layer-1 aggregate + softmax + ELU + layer-2 MFMA projection ---
// block = 16 nodes: 4 waves x 4-node serial loop; g1 tile in LDS with PADDED
// stride 136 (epilogue reads land 2-way per bank = free); epilogue waves 0-2.
__global__ __launch_bounds__(256) void agg1g2_kernel(
    const f16* __restrict__ h1, const float* __restrict__ as1,
    const float* __restrict__ ad1, const int* __restrict__ rowptr,
    const int* __restrict__ csr, const f16* __restrict__ W2p,
    f16* __restrict__ h2, float* __restrict__ as2, float* __restrict__ ad2) {
  __shared__ f16 g1s[16 * 136];     // padded stride breaks 16-way conflict
  const int t = threadIdx.x;
  const int lane = t & 63;
  const int w = t >> 6;
  const int j = lane >> 3, hd = lane & 7;
  const int q = lane >> 4;          // PV edge sub-slot (0..3)
  const int part = lane & 15;       // 8-feature block
  const int base_node = blockIdx.x * 16 + w * 4;
  for (int ii = 0; ii < 4; ++ii) {
    const int wid = base_node + ii;
    const int lo = rowptr[wid], hi = rowptr[wid + 1];
    const int deg = hi - lo;
    const float advv = ad1[wid * 8 + hd];
    float lk0 = -3.4e38f, lk1 = -3.4e38f, lk2 = -3.4e38f, lk3 = -3.4e38f;
    int s0 = 0, s1 = 0, s2 = 0, s3 = 0;
    if (j < deg)      { s0 = csr[lo + j];      lk0 = leaky02(as1[(size_t)s0 * 8 + hd] + advv); }
    if (8 + j < deg)  { s1 = csr[lo + 8 + j];  lk1 = leaky02(as1[(size_t)s1 * 8 + hd] + advv); }
    if (16 + j < deg) { s2 = csr[lo + 16 + j]; lk2 = leaky02(as1[(size_t)s2 * 8 + hd] + advv); }
    if (24 + j < deg) { s3 = csr[lo + 24 + j]; lk3 = leaky02(as1[(size_t)s3 * 8 + hd] + advv); }
    float m = fmaxf(fmaxf(lk0, lk1), fmaxf(lk2, lk3));
    for (int base = 32; base < deg; base += 8) {   // rare tail
      int e = base + j;
      float xv = (e < deg) ? leaky02(as1[(size_t)csr[lo + e] * 8 + hd] + advv)
                           : -3.4e38f;
      m = fmaxf(m, xv);
    }
    m = fmaxf(m, __shfl_xor(m, 8));
    m = fmaxf(m, __shfl_xor(m, 16));
    m = fmaxf(m, __shfl_xor(m, 32));
    float sum = 0.f;
    float acc[8];
#pragma unroll
    for (int i = 0; i < 8; ++i) acc[i] = 0.f;
    for (int base = 0; base < deg; base += 8) {
      int e = base + j;
      float p = 0.f;
      int s = 0;
      if (base == 0)       { s = s0; if (e < deg) p = __expf(lk0 - m); }
      else if (base == 8)  { s = s1; if (e < deg) p = __expf(lk1 - m); }
      else if (base == 16) { s = s2; if (e < deg) p = __expf(lk2 - m); }
      else if (base == 24) { s = s3; if (e < deg) p = __expf(lk3 - m); }
      else if (e < deg) {
        s = csr[lo + e];
        p = __expf(leaky02(as1[(size_t)s * 8 + hd] + advv) - m);
      }
      sum += p;
      int sja = __shfl(s, q * 8);
      float pja = __shfl(p, q * 8 + (part >> 1));
      int sjb = __shfl(s, (4 + q) * 8);
      float pjb = __shfl(p, (4 + q) * 8 + (part >> 1));
      f16x8 hva = *(const f16x8*)(h1 + (size_t)sja * 128 + part * 8);
      f16x8 hvb = *(const f16x8*)(h1 + (size_t)sjb * 128 + part * 8);
#pragma unroll
      for (int i = 0; i < 8; ++i) acc[i] += pja * (float)hva[i];
#pragma unroll
      for (int i = 0; i < 8; ++i) acc[i] += pjb * (float)hvb[i];
    }
    sum += __shfl_xor(sum, 8);
    sum += __shfl_xor(sum, 16);
    sum += __shfl_xor(sum, 32);
#pragma unroll
    for (int i = 0; i < 8; ++i) {
      acc[i] += __shfl_xor(acc[i], 16);
      acc[i] += __shfl_xor(acc[i], 32);
    }
    float sden = __shfl(sum, part >> 1);
    float inv = 1.f / fmaxf(sden, 1e-16f);
    if (lane < 16) {
      f16x8 ov;
#pragma unroll
      for (int i = 0; i < 8; ++i) {
        float v = acc[i] * inv;
        v = v > 0.f ? v : (__expf(v) - 1.f);
        ov[i] = (f16)v;
      }
      *(f16x8*)&g1s[(w * 4 + ii) * 136 + part * 8] = ov;
    }
  }
  __syncthreads();
  // ---- gemm2 epilogue: wave w handles ct-tile w (w < 3) ----
  if (w < 3) {
    const int rsub = lane & 15, kg = lane >> 4;
    const f16* ap = &g1s[rsub * 136 + kg * 8];
    f16x8 a0 = *(const f16x8*)(ap);
    f16x8 a1 = *(const f16x8*)(ap + 32);
    f16x8 a2 = *(const f16x8*)(ap + 64);
    f16x8 a3 = *(const f16x8*)(ap + 96);
    const f16x8* bp = (const f16x8*)W2p;
    f32x4 acc2 = { 0.f, 0.f, 0.f, 0.f };
    acc2 = __builtin_amdgcn_mfma_f32_16x16x32_f16(a0, bp[(0 * 4 + w) * 64 + lane], acc2, 0, 0, 0);
    acc2 = __builtin_amdgcn_mfma_f32_16x16x32_f16(a1, bp[(1 * 4 + w) * 64 + lane], acc2, 0, 0, 0);
    acc2 = __builtin_amdgcn_mfma_f32_16x16x32_f16(a2, bp[(2 * 4 + w) * 64 + lane], acc2, 0, 0, 0);
    acc2 = __builtin_amdgcn_mfma_f32_16x16x32_f16(a3, bp[(3 * 4 + w) * 64 + lane], acc2, 0, 0, 0);
    const int r0 = blockIdx.x * 16 + kg * 4;
    const int col = w * 16 + rsub;
    if (col < 40) {
#pragma unroll
      for (int r = 0; r < 4; ++r)
        h2[(size_t)(r0 + r) * 40 + col] = (f16)acc2[r];
    }
    if (w == 2) {
      if (rsub == 8) {          // col 40: src logits
#pragma unroll
        for (int r = 0; r < 4; ++r) as2[r0 + r] = acc2[r];
      } else if (rsub == 9) {   // col 41: dst logits
#pragma unroll
        for (int r = 0; r < 4; ++r) ad2[r0 + r] = acc2[r];
      }
    }
  }
}

// ---------------- layer-2 aggregate + softmax -> d_out ----------------
__global__ __launch_bounds__(256) void agg2_kernel(
    const f16* __restrict__ h2, const float* __restrict__ as2,
    const float* __restrict__ ad2, const int* __restrict__ rowptr,
    const int* __restrict__ csr, const float* __restrict__ b2,
    float* __restrict__ out) {
  const int wid = (blockIdx.x * 256 + threadIdx.x) >> 6;
  const int lane = threadIdx.x & 63;
  if (wid >= NN) return;
  const int lo = rowptr[wid], hi = rowptr[wid + 1];
  const int deg = hi - lo;
  const float advv = ad2[wid];
  float lkc = -3.4e38f;
  int sc = 0;
  if (lane < deg) {
    sc = csr[lo + lane];
    lkc = leaky02(as2[sc] + advv);
  }
  float m = lkc;
  for (int base = 64; base < deg; base += 64) {   // rare tail
    int e = base + lane;
    float xv = (e < deg) ? leaky02(as2[csr[lo + e]] + advv) : -3.4e38f;
    m = fmaxf(m, xv);
  }
#pragma unroll
  for (int off = 32; off >= 1; off >>= 1) m = fmaxf(m, __shfl_xor(m, off));
  const int j8 = lane >> 3, part8 = lane & 7;
  const bool pvon = part8 < 5;
  float sum = 0.f;
  float acc[8];
#pragma unroll
  for (int i = 0; i < 8; ++i) acc[i] = 0.f;
  for (int base = 0; base < deg; base += 64) {
    int e = base + lane;
    float p = 0.f;
    int s = 0;
    if (base == 0) {
      s = sc;
      if (lane < deg) p = __expf(lkc - m);
    } else if (e < deg) {
      s = csr[lo + e];
      p = __expf(leaky02(as2[s] + advv) - m);
    }
    sum += p;
    const int ng = (min(64, deg - base) + 7) >> 3;
    int g = 0;
    for (; g + 1 < ng; g += 2) {
      int sl1 = g * 8 + j8, sl2 = (g + 1) * 8 + j8;
      int sj1 = __shfl(s, sl1);
      float pj1 = __shfl(p, sl1);
      int sj2 = __shfl(s, sl2);
      float pj2 = __shfl(p, sl2);
      if (pvon) {
        f16x8 hv1 = *(const f16x8*)(h2 + (size_t)sj1 * 40 + part8 * 8);
        f16x8 hv2 = *(const f16x8*)(h2 + (size_t)sj2 * 40 + part8 * 8);
#pragma unroll
        for (int i = 0; i < 8; ++i) acc[i] += pj1 * (float)hv1[i];
#pragma unroll
        for (int i = 0; i < 8; ++i) acc[i] += pj2 * (float)hv2[i];
      }
    }
    if (g < ng) {
      int sl = g * 8 + j8;
      int sj = __shfl(s, sl);
      float pj = __shfl(p, sl);
      if (pvon) {
        f16x8 hv = *(const f16x8*)(h2 + (size_t)sj * 40 + part8 * 8);
#pragma unroll
        for (int i = 0; i < 8; ++i) acc[i] += pj * (float)hv[i];
      }
    }
  }
#pragma unroll
  for (int off = 32; off >= 1; off >>= 1) sum += __shfl_xor(sum, off);
#pragma unroll
  for (int i = 0; i < 8; ++i) {
    acc[i] += __shfl_xor(acc[i], 8);
    acc[i] += __shfl_xor(acc[i], 16);
    acc[i] += __shfl_xor(acc[i], 32);
  }
  const float inv = 1.f / fmaxf(sum, 1e-16f);
  if (lane < 5) {   // j8 == 0, part8 == lane -> cols lane*8 .. lane*8+7
    float4 b0 = *(const float4*)(b2 + lane * 8);
    float4 b1 = *(const float4*)(b2 + lane * 8 + 4);
    float4 v0 = { acc[0] * inv + b0.x, acc[1] * inv + b0.y,
                  acc[2] * inv + b0.z, acc[3] * inv + b0.w };
    float4 v1 = { acc[4] * inv + b1.x, acc[5] * inv + b1.y,
                  acc[6] * inv + b1.z, acc[7] * inv + b1.w };
    *(float4*)(out + (size_t)wid * 40 + lane * 8) = v0;
    *(float4*)(out + (size_t)wid * 40 + lane * 8 + 4) = v1;
  }
}

extern "C" void kernel_launch(void* const* d_in, const int* in_sizes, int n_in,
                              void* d_out, int out_size, void* d_ws, size_t ws_size,
                              hipStream_t stream) {
  (void)in_sizes; (void)n_in; (void)out_size; (void)ws_size;
  const float* x = (const float*)d_in[0];
  const void* esrc = d_in[1];
  const void* edst = d_in[2];
  const float* W1 = (const float*)d_in[3];
  const float* att_s1 = (const float*)d_in[4];
  const float* att_d1 = (const float*)d_in[5];
  const float* W2 = (const float*)d_in[7];
  const float* att_s2 = (const float*)d_in[8];
  const float* att_d2 = (const float*)d_in[9];
  const float* b2 = (const float*)d_in[10];

  char* p = (char*)d_ws;
  auto alloc = [&](size_t bytes) {
    char* q = p;
    p += (bytes + 255) & ~(size_t)255;
    return q;
  };
  f16* h1 = (f16*)alloc((size_t)NN * 128 * 2);
  f16* h2 = (f16*)alloc((size_t)NN * 40 * 2);
  float* as1 = (float*)alloc((size_t)NN * 8 * 4);
  float* ad1 = (float*)alloc((size_t)NN * 8 * 4);
  float* as2 = (float*)alloc((size_t)NN * 4);
  float* ad2 = (float*)alloc((size_t)NN * 4);
  f16* W2p = (f16*)alloc((size_t)8192 * 2);
  float* w1b2 = (float*)alloc((size_t)128 * 16 * 4);
  int* rowptr = (int*)alloc((size_t)(NN + 1) * 4);
  int* csr = (int*)alloc((size_t)NE * 4);
  unsigned int* bucketbuf = (unsigned int*)alloc((size_t)NE * 4);
  int* gbucket = (int*)alloc((size_t)NBKT * 4);
  int* bb = (int*)alloc((size_t)(NBKT + 1) * 4);
  int* bcur = (int*)alloc((size_t)NBKT * 4);
  int* flag = (int*)alloc(256);

  prepdet_kernel<<<4, 256, 0, stream>>>(W1, att_s1, att_d1, W2, att_s2,
                                        att_d2, (const int*)esrc, W2p, w1b2,
                                        flag, gbucket);
  g1bc_kernel<<<G1BLKS + BCBLKS, 256, 0, stream>>>(x, W1, w1b2, h1, as1, ad1,
                                                   edst, flag, gbucket);
  bucketscan_kernel<<<1, 512, 0, stream>>>(gbucket, bb, bcur);
  partition_kernel<<<P2BLKS, 256, 0, stream>>>(esrc, edst, flag, bcur, bucketbuf);
  build_kernel<<<NBKT, 256, 0, stream>>>(bucketbuf, bb, rowptr, csr);
  agg1g2_kernel<<<6250, 256, 0, stream>>>(h1, as1, ad1, rowptr, csr, W2p,
                                          h2, as2, ad2);
  agg2_kernel<<<25000, 256, 0, stream>>>(h2, as2, ad2, rowptr, csr, b2,
                                         (float*)d_out);
}

// Round 19
// 241.866 us; speedup vs baseline: 1.0477x; 1.0095x over previous
//
#include <hip/hip_runtime.h>
#include <cstdint>
#include <cstddef>

#define NN 100000
#define NE 1600000
#define NH 8
#define NC 40
#define NBKT 391            // ceil(NN / 256)
#define CHUNK 4096
#define P2BLKS ((NE + CHUNK - 1) / CHUNK)
#define G1BLKS 1563         // gemm1 blocks
#define BCBLKS 256          // bucketcnt blocks fused into prep kernel

typedef _Float16 f16;
typedef f16 f16x2 __attribute__((ext_vector_type(2)));
typedef f16 f16x4 __attribute__((ext_vector_type(4)));
typedef f16 f16x8 __attribute__((ext_vector_type(8)));
typedef float f32x4 __attribute__((ext_vector_type(4)));

static __device__ __forceinline__ float leaky02(float x) {
  return x >= 0.f ? x : 0.2f * x;
}

static __device__ __forceinline__ int edge_at(const void* p, int is32, int i) {
  return is32 ? ((const int*)p)[i] : (int)((const long long*)p)[i];
}

// ---- prep + bucketcnt (259 blocks): b0 W2p, b1 w1b2, b2 detect->flag,
// b3..258 bucketcnt (per-block inline int-width detection, no flag dep).
__global__ __launch_bounds__(256) void prepbc_kernel(
    const float* __restrict__ W1, const float* __restrict__ att_src,
    const float* __restrict__ att_dst, const float* __restrict__ W2,
    const float* __restrict__ as2v, const float* __restrict__ ad2v,
    const int* __restrict__ esrc32, const void* __restrict__ edst,
    f16* __restrict__ W2p, float* __restrict__ w1b2,
    int* __restrict__ flag, int* __restrict__ gbucket) {
  __shared__ int lflag;
  __shared__ int hcnt[NBKT];
  const int t = threadIdx.x;
  if (blockIdx.x == 0) {
    for (int i = t; i < 8192; i += 256) {
      const int e = i & 7, lane = (i >> 3) & 63, tt = (i >> 9) & 3, s = (i >> 11) & 3;
      const int k = 32 * s + ((lane >> 4) << 3) + e;
      const int c = 16 * tt + (lane & 15);
      float v = 0.f;
      if (c < 40) {
        v = W2[k * 40 + c];
      } else if (c == 40 || c == 41) {
        const float* a = (c == 40) ? as2v : ad2v;
        float sacc = 0.f;
#pragma unroll 8
        for (int j = 0; j < 40; ++j) sacc += W2[k * 40 + j] * a[j];
        v = sacc;
      }
      W2p[i] = (f16)v;
    }
  } else if (blockIdx.x == 1) {
    const int k = t;
    if (k < 128) {
#pragma unroll
      for (int col = 0; col < 16; ++col) {
        const int h = col & 7;
        const float* av = (col < 8) ? att_src : att_dst;
        float v = 0.f;
#pragma unroll
        for (int f = 0; f < 16; ++f)
          v += W1[k * 128 + h * 16 + f] * av[h * 16 + f];
        w1b2[k * 16 + col] = v;
      }
    }
  } else if (blockIdx.x == 2) {
    if (t == 0) lflag = 0;
    __syncthreads();
    for (int i = t; i < 1024; i += 256)
      if (esrc32[2 * i + 1] != 0) atomicOr(&lflag, 1);
    __syncthreads();
    if (t == 0) *flag = lflag;
  } else {
    // ---- bucketcnt with per-block detection ----
    if (t == 0) lflag = 0;
    for (int i = t; i < NBKT; i += 256) hcnt[i] = 0;
    __syncthreads();
    int f = 0;
    const int* e32 = (const int*)edst;
    for (int i = t; i < 1024; i += 256) f |= (e32[2 * i + 1] != 0);
    if (__any(f)) { if ((t & 63) == 0) atomicOr(&lflag, 1); }
    __syncthreads();
    const int is32 = lflag;
    const int bid = blockIdx.x - 3;
    int i = bid * 256 + t;
    const int st = BCBLKS * 256;
    for (; i < NE; i += st) atomicAdd(&hcnt[edge_at(edst, is32, i) >> 8], 1);
    __syncthreads();
    for (int b = t; b < NBKT; b += 256)
      if (hcnt[b]) atomicAdd(&gbucket[b], hcnt[b]);
  }
}

// ------- fused: gemm1 (MFMA, blocks <G1BLKS) + partition (blocks >=G1BLKS) --
__global__ __launch_bounds__(256) void g1part_kernel(
    const float* __restrict__ x, const float* __restrict__ W1,
    const float* __restrict__ w1b2, f16* __restrict__ h1,
    float* __restrict__ as1, float* __restrict__ ad1,
    const void* __restrict__ esrc, const void* __restrict__ edst,
    const int* __restrict__ flag, int* __restrict__ bcur,
    unsigned int* __restrict__ bucketbuf) {
  __shared__ f16 wp[16384];    // [kt][ct][lane][e]
  __shared__ f16 wp2[2048];    // [kt][lane][e]
  __shared__ int h[NBKT];
  __shared__ int gb[NBKT];
  const int t = threadIdx.x;
  if (blockIdx.x >= G1BLKS) {
    // ---- partition part ----
    const int is32 = *flag;
    const int lo = (blockIdx.x - G1BLKS) * CHUNK;
    const int hi = min(lo + CHUNK, NE);
    for (int i = t; i < NBKT; i += 256) h[i] = 0;
    __syncthreads();
    for (int i = lo + t; i < hi; i += 256)
      atomicAdd(&h[edge_at(edst, is32, i) >> 8], 1);
    __syncthreads();
    for (int b = t; b < NBKT; b += 256)
      gb[b] = h[b] ? atomicAdd(&bcur[b], h[b]) : 0;
    __syncthreads();
    for (int i = t; i < NBKT; i += 256) h[i] = 0;   // reuse as local cursor
    __syncthreads();
    for (int i = lo + t; i < hi; i += 256) {
      int d = edge_at(edst, is32, i);
      int b = d >> 8;
      int s = atomicAdd(&h[b], 1);
      bucketbuf[gb[b] + s] =
          ((unsigned)(d & 255) << 17) | (unsigned)edge_at(esrc, is32, i);
    }
    return;
  }
  // ---- gemm1 part ----
  for (int i = t; i < 16384; i += 256) {
    const int e = i & 7, ln = (i >> 3) & 63, ct = (i >> 9) & 7, kt = i >> 12;
    const int k = kt * 32 + ((ln >> 4) << 3) + e;
    const int c = ct * 16 + (ln & 15);
    wp[i] = (f16)W1[k * 128 + c];
  }
  for (int i = t; i < 2048; i += 256) {
    const int e = i & 7, ln = (i >> 3) & 63, kt = i >> 9;
    const int k = kt * 32 + ((ln >> 4) << 3) + e;
    const int col = ln & 15;
    wp2[i] = (f16)w1b2[k * 16 + col];
  }
  __syncthreads();
  const int lane = t & 63;
  const int rsub = lane & 15, kg = lane >> 4;
  const int wid = (blockIdx.x * 256 + t) >> 6;
  if (wid >= NN / 16) return;
  const int row0 = wid * 16;
  const float* ap = x + (size_t)(row0 + rsub) * 128 + kg * 8;
  f16x8 a[4];
#pragma unroll
  for (int kt = 0; kt < 4; ++kt) {
    float4 v0 = *(const float4*)(ap + kt * 32);
    float4 v1 = *(const float4*)(ap + kt * 32 + 4);
    f16x8 av = { (f16)v0.x, (f16)v0.y, (f16)v0.z, (f16)v0.w,
                 (f16)v1.x, (f16)v1.y, (f16)v1.z, (f16)v1.w };
    a[kt] = av;
  }
  const f16x8* bp = (const f16x8*)wp;
  const f16x8* bp2 = (const f16x8*)wp2;
  const f32x4 z4 = { 0.f, 0.f, 0.f, 0.f };
  f32x4 acc[8];
#pragma unroll
  for (int ct = 0; ct < 8; ++ct) acc[ct] = z4;
  f32x4 acc2 = z4;
#pragma unroll
  for (int kt = 0; kt < 4; ++kt) {
#pragma unroll
    for (int ct = 0; ct < 8; ++ct)
      acc[ct] = __builtin_amdgcn_mfma_f32_16x16x32_f16(
          a[kt], bp[(kt * 8 + ct) * 64 + lane], acc[ct], 0, 0, 0);
    acc2 = __builtin_amdgcn_mfma_f32_16x16x32_f16(
        a[kt], bp2[kt * 64 + lane], acc2, 0, 0, 0);
  }
  const int r0 = row0 + kg * 4;
#pragma unroll
  for (int ct = 0; ct < 8; ++ct) {
#pragma unroll
    for (int r = 0; r < 4; ++r)
      h1[(size_t)(r0 + r) * 128 + ct * 16 + rsub] = (f16)acc[ct][r];
  }
#pragma unroll
  for (int r = 0; r < 4; ++r) {
    if (rsub < 8) as1[(r0 + r) * 8 + rsub] = acc2[r];
    else          ad1[(r0 + r) * 8 + rsub - 8] = acc2[r];
  }
}

// ---------------- CSR build: scan -> (partition fused above) -> build -------
__global__ __launch_bounds__(512) void bucketscan_kernel(
    const int* __restrict__ gbucket, int* __restrict__ bb,
    int* __restrict__ bcur) {
  __shared__ int wsum[8];
  const int t = threadIdx.x;
  const int lane = t & 63, w = t >> 6;
  int v = (t < NBKT) ? gbucket[t] : 0;
  int sc = v;
#pragma unroll
  for (int off = 1; off < 64; off <<= 1) {
    int o = __shfl_up(sc, off);
    if (lane >= off) sc += o;
  }
  if (lane == 63) wsum[w] = sc;
  __syncthreads();
  if (t < 8) {
    int ws = wsum[t];
#pragma unroll
    for (int off = 1; off < 8; off <<= 1) {
      int o = __shfl_up(ws, off);
      if (t >= off) ws += o;
    }
    wsum[t] = ws;
  }
  __syncthreads();
  if (w > 0) sc += wsum[w - 1];
  if (t < NBKT) {
    int ex = sc - v;
    bb[t] = ex;
    bcur[t] = ex;
  }
  if (t == NBKT - 1) bb[NBKT] = sc;   // == NE
}

__global__ __launch_bounds__(256) void build_kernel(
    const unsigned int* __restrict__ bucketbuf, const int* __restrict__ bb,
    int* __restrict__ rowptr, int* __restrict__ csr) {
  __shared__ int cnt[256];
  __shared__ int cur[256];
  __shared__ int wsum[4];
  const int k = blockIdx.x;
  const int t = threadIdx.x;
  const int node0 = k << 8;
  const int lo = bb[k], hi = bb[k + 1];
  cnt[t] = 0;
  __syncthreads();
  for (int i = lo + t; i < hi; i += 256)
    atomicAdd(&cnt[bucketbuf[i] >> 17], 1);
  __syncthreads();
  const int lane = t & 63, w = t >> 6;
  const int v = cnt[t];
  int sc = v;
#pragma unroll
  for (int off = 1; off < 64; off <<= 1) {
    int o = __shfl_up(sc, off);
    if (lane >= off) sc += o;
  }
  if (lane == 63) wsum[w] = sc;
  __syncthreads();
  if (t < 4) {
    int ws = wsum[t];
#pragma unroll
    for (int off = 1; off < 4; off <<= 1) {
      int o = __shfl_up(ws, off);
      if (t >= off) ws += o;
    }
    wsum[t] = ws;
  }
  __syncthreads();
  if (w > 0) sc += wsum[w - 1];
  const int ex = lo + sc - v;
  const int node = node0 + t;
  if (node < NN) rowptr[node] = ex;
  if (node == NN - 1) rowptr[NN] = NE;
  cur[t] = ex;
  __syncthreads();
  for (int i = lo + t; i < hi; i += 256) {
    unsigned e = bucketbuf[i];
    int pos = atomicAdd(&cur[e >> 17], 1);
    csr[pos] = (int)(e & 0x1FFFF);
  }
}

// --- fused layer-1 aggregate + softmax + ELU + layer-2 MFMA projection ---
// block = 16 nodes: 4 waves x 4-node serial loop; g1 tile in LDS padded 136.
__global__ __launch_bounds__(256) void agg1g2_kernel(
    const f16* __restrict__ h1, const float* __restrict__ as1,
    const float* __restrict__ ad1, const int* __restrict__ rowptr,
    const int* __restrict__ csr, const f16* __restrict__ W2p,
    f16* __restrict__ h2, float* __restrict__ as2, float* __restrict__ ad2) {
  __shared__ f16 g1s[16 * 136];
  const int t = threadIdx.x;
  const int lane = t & 63;
  const int w = t >> 6;
  const int j = lane >> 3, hd = lane & 7;
  const int q = lane >> 4;          // PV edge sub-slot (0..3)
  const int part = lane & 15;       // 8-feature block
  const int base_node = blockIdx.x * 16 + w * 4;
  for (int ii = 0; ii < 4; ++ii) {
    const int wid = base_node + ii;
    const int lo = rowptr[wid], hi = rowptr[wid + 1];
    const int deg = hi - lo;
    const float advv = ad1[wid * 8 + hd];
    float lk0 = -3.4e38f, lk1 = -3.4e38f, lk2 = -3.4e38f, lk3 = -3.4e38f;
    int s0 = 0, s1 = 0, s2 = 0, s3 = 0;
    if (j < deg)      { s0 = csr[lo + j];      lk0 = leaky02(as1[(size_t)s0 * 8 + hd] + advv); }
    if (8 + j < deg)  { s1 = csr[lo + 8 + j];  lk1 = leaky02(as1[(size_t)s1 * 8 + hd] + advv); }
    if (16 + j < deg) { s2 = csr[lo + 16 + j]; lk2 = leaky02(as1[(size_t)s2 * 8 + hd] + advv); }
    if (24 + j < deg) { s3 = csr[lo + 24 + j]; lk3 = leaky02(as1[(size_t)s3 * 8 + hd] + advv); }
    float m = fmaxf(fmaxf(lk0, lk1), fmaxf(lk2, lk3));
    for (int base = 32; base < deg; base += 8) {   // rare tail
      int e = base + j;
      float xv = (e < deg) ? leaky02(as1[(size_t)csr[lo + e] * 8 + hd] + advv)
                           : -3.4e38f;
      m = fmaxf(m, xv);
    }
    m = fmaxf(m, __shfl_xor(m, 8));
    m = fmaxf(m, __shfl_xor(m, 16));
    m = fmaxf(m, __shfl_xor(m, 32));
    float sum = 0.f;
    float acc[8];
#pragma unroll
    for (int i = 0; i < 8; ++i) acc[i] = 0.f;
    for (int base = 0; base < deg; base += 8) {
      int e = base + j;
      float p = 0.f;
      int s = 0;
      if (base == 0)       { s = s0; if (e < deg) p = __expf(lk0 - m); }
      else if (base == 8)  { s = s1; if (e < deg) p = __expf(lk1 - m); }
      else if (base == 16) { s = s2; if (e < deg) p = __expf(lk2 - m); }
      else if (base == 24) { s = s3; if (e < deg) p = __expf(lk3 - m); }
      else if (e < deg) {
        s = csr[lo + e];
        p = __expf(leaky02(as1[(size_t)s * 8 + hd] + advv) - m);
      }
      sum += p;
      int sja = __shfl(s, q * 8);
      float pja = __shfl(p, q * 8 + (part >> 1));
      int sjb = __shfl(s, (4 + q) * 8);
      float pjb = __shfl(p, (4 + q) * 8 + (part >> 1));
      f16x8 hva = *(const f16x8*)(h1 + (size_t)sja * 128 + part * 8);
      f16x8 hvb = *(const f16x8*)(h1 + (size_t)sjb * 128 + part * 8);
#pragma unroll
      for (int i = 0; i < 8; ++i) acc[i] += pja * (float)hva[i];
#pragma unroll
      for (int i = 0; i < 8; ++i) acc[i] += pjb * (float)hvb[i];
    }
    sum += __shfl_xor(sum, 8);
    sum += __shfl_xor(sum, 16);
    sum += __shfl_xor(sum, 32);
#pragma unroll
    for (int i = 0; i < 8; ++i) {
      acc[i] += __shfl_xor(acc[i], 16);
      acc[i] += __shfl_xor(acc[i], 32);
    }
    float sden = __shfl(sum, part >> 1);
    float inv = 1.f / fmaxf(sden, 1e-16f);
    if (lane < 16) {
      f16x8 ov;
#pragma unroll
      for (int i = 0; i < 8; ++i) {
        float v = acc[i] * inv;
        v = v > 0.f ? v : (__expf(v) - 1.f);
        ov[i] = (f16)v;
      }
      *(f16x8*)&g1s[(w * 4 + ii) * 136 + part * 8] = ov;
    }
  }
  __syncthreads();
  // ---- gemm2 epilogue: wave w handles ct-tile w (w < 3) ----
  if (w < 3) {
    const int rsub = lane & 15, kg = lane >> 4;
    const f16* ap = &g1s[rsub * 136 + kg * 8];
    f16x8 a0 = *(const f16x8*)(ap);
    f16x8 a1 = *(const f16x8*)(ap + 32);
    f16x8 a2 = *(const f16x8*)(ap + 64);
    f16x8 a3 = *(const f16x8*)(ap + 96);
    const f16x8* bp = (const f16x8*)W2p;
    f32x4 acc2 = { 0.f, 0.f, 0.f, 0.f };
    acc2 = __builtin_amdgcn_mfma_f32_16x16x32_f16(a0, bp[(0 * 4 + w) * 64 + lane], acc2, 0, 0, 0);
    acc2 = __builtin_amdgcn_mfma_f32_16x16x32_f16(a1, bp[(1 * 4 + w) * 64 + lane], acc2, 0, 0, 0);
    acc2 = __builtin_amdgcn_mfma_f32_16x16x32_f16(a2, bp[(2 * 4 + w) * 64 + lane], acc2, 0, 0, 0);
    acc2 = __builtin_amdgcn_mfma_f32_16x16x32_f16(a3, bp[(3 * 4 + w) * 64 + lane], acc2, 0, 0, 0);
    const int r0 = blockIdx.x * 16 + kg * 4;
    const int col = w * 16 + rsub;
    if (col < 40) {
#pragma unroll
      for (int r = 0; r < 4; ++r)
        h2[(size_t)(r0 + r) * 40 + col] = (f16)acc2[r];
    }
    if (w == 2) {
      if (rsub == 8) {          // col 40: src logits
#pragma unroll
        for (int r = 0; r < 4; ++r) as2[r0 + r] = acc2[r];
      } else if (rsub == 9) {   // col 41: dst logits
#pragma unroll
        for (int r = 0; r < 4; ++r) ad2[r0 + r] = acc2[r];
      }
    }
  }
}

// ---------------- layer-2 aggregate + softmax -> d_out ----------------
__global__ __launch_bounds__(256) void agg2_kernel(
    const f16* __restrict__ h2, const float* __restrict__ as2,
    const float* __restrict__ ad2, const int* __restrict__ rowptr,
    const int* __restrict__ csr, const float* __restrict__ b2,
    float* __restrict__ out) {
  const int wid = (blockIdx.x * 256 + threadIdx.x) >> 6;
  const int lane = threadIdx.x & 63;
  if (wid >= NN) return;
  const int lo = rowptr[wid], hi = rowptr[wid + 1];
  const int deg = hi - lo;
  const float advv = ad2[wid];
  float lkc = -3.4e38f;
  int sc = 0;
  if (lane < deg) {
    sc = csr[lo + lane];
    lkc = leaky02(as2[sc] + advv);
  }
  float m = lkc;
  for (int base = 64; base < deg; base += 64) {   // rare tail
    int e = base + lane;
    float xv = (e < deg) ? leaky02(as2[csr[lo + e]] + advv) : -3.4e38f;
    m = fmaxf(m, xv);
  }
#pragma unroll
  for (int off = 32; off >= 1; off >>= 1) m = fmaxf(m, __shfl_xor(m, off));
  const int j8 = lane >> 3, part8 = lane & 7;
  const bool pvon = part8 < 5;
  float sum = 0.f;
  float acc[8];
#pragma unroll
  for (int i = 0; i < 8; ++i) acc[i] = 0.f;
  for (int base = 0; base < deg; base += 64) {
    int e = base + lane;
    float p = 0.f;
    int s = 0;
    if (base == 0) {
      s = sc;
      if (lane < deg) p = __expf(lkc - m);
    } else if (e < deg) {
      s = csr[lo + e];
      p = __expf(leaky02(as2[s] + advv) - m);
    }
    sum += p;
    const int ng = (min(64, deg - base) + 7) >> 3;
    int g = 0;
    for (; g + 1 < ng; g += 2) {
      int sl1 = g * 8 + j8, sl2 = (g + 1) * 8 + j8;
      int sj1 = __shfl(s, sl1);
      float pj1 = __shfl(p, sl1);
      int sj2 = __shfl(s, sl2);
      float pj2 = __shfl(p, sl2);
      if (pvon) {
        f16x8 hv1 = *(const f16x8*)(h2 + (size_t)sj1 * 40 + part8 * 8);
        f16x8 hv2 = *(const f16x8*)(h2 + (size_t)sj2 * 40 + part8 * 8);
#pragma unroll
        for (int i = 0; i < 8; ++i) acc[i] += pj1 * (float)hv1[i];
#pragma unroll
        for (int i = 0; i < 8; ++i) acc[i] += pj2 * (float)hv2[i];
      }
    }
    if (g < ng) {
      int sl = g * 8 + j8;
      int sj = __shfl(s, sl);
      float pj = __shfl(p, sl);
      if (pvon) {
        f16x8 hv = *(const f16x8*)(h2 + (size_t)sj * 40 + part8 * 8);
#pragma unroll
        for (int i = 0; i < 8; ++i) acc[i] += pj * (float)hv[i];
      }
    }
  }
#pragma unroll
  for (int off = 32; off >= 1; off >>= 1) sum += __shfl_xor(sum, off);
#pragma unroll
  for (int i = 0; i < 8; ++i) {
    acc[i] += __shfl_xor(acc[i], 8);
    acc[i] += __shfl_xor(acc[i], 16);
    acc[i] += __shfl_xor(acc[i], 32);
  }
  const float inv = 1.f / fmaxf(sum, 1e-16f);
  if (lane < 5) {   // j8 == 0, part8 == lane -> cols lane*8 .. lane*8+7
    float4 b0 = *(const float4*)(b2 + lane * 8);
    float4 b1 = *(const float4*)(b2 + lane * 8 + 4);
    float4 v0 = { acc[0] * inv + b0.x, acc[1] * inv + b0.y,
                  acc[2] * inv + b0.z, acc[3] * inv + b0.w };
    float4 v1 = { acc[4] * inv + b1.x, acc[5] * inv + b1.y,
                  acc[6] * inv + b1.z, acc[7] * inv + b1.w };
    *(float4*)(out + (size_t)wid * 40 + lane * 8) = v0;
    *(float4*)(out + (size_t)wid * 40 + lane * 8 + 4) = v1;
  }
}

extern "C" void kernel_launch(void* const* d_in, const int* in_sizes, int n_in,
                              void* d_out, int out_size, void* d_ws, size_t ws_size,
                              hipStream_t stream) {
  (void)in_sizes; (void)n_in; (void)out_size; (void)ws_size;
  const float* x = (const float*)d_in[0];
  const void* esrc = d_in[1];
  const void* edst = d_in[2];
  const float* W1 = (const float*)d_in[3];
  const float* att_s1 = (const float*)d_in[4];
  const float* att_d1 = (const float*)d_in[5];
  const float* W2 = (const float*)d_in[7];
  const float* att_s2 = (const float*)d_in[8];
  const float* att_d2 = (const float*)d_in[9];
  const float* b2 = (const float*)d_in[10];

  char* p = (char*)d_ws;
  auto alloc = [&](size_t bytes) {
    char* q = p;
    p += (bytes + 255) & ~(size_t)255;
    return q;
  };
  f16* h1 = (f16*)alloc((size_t)NN * 128 * 2);
  f16* h2 = (f16*)alloc((size_t)NN * 40 * 2);
  float* as1 = (float*)alloc((size_t)NN * 8 * 4);
  float* ad1 = (float*)alloc((size_t)NN * 8 * 4);
  float* as2 = (float*)alloc((size_t)NN * 4);
  float* ad2 = (float*)alloc((size_t)NN * 4);
  f16* W2p = (f16*)alloc((size_t)8192 * 2);
  float* w1b2 = (float*)alloc((size_t)128 * 16 * 4);
  int* rowptr = (int*)alloc((size_t)(NN + 1) * 4);
  int* csr = (int*)alloc((size_t)NE * 4);
  unsigned int* bucketbuf = (unsigned int*)alloc((size_t)NE * 4);
  int* gbucket = (int*)alloc((size_t)NBKT * 4);
  int* bb = (int*)alloc((size_t)(NBKT + 1) * 4);
  int* bcur = (int*)alloc((size_t)NBKT * 4);
  int* flag = (int*)alloc(256);

  hipMemsetAsync(gbucket, 0, (size_t)NBKT * 4, stream);
  prepbc_kernel<<<3 + BCBLKS, 256, 0, stream>>>(
      W1, att_s1, att_d1, W2, att_s2, att_d2, (const int*)esrc, edst,
      W2p, w1b2, flag, gbucket);
  bucketscan_kernel<<<1, 512, 0, stream>>>(gbucket, bb, bcur);
  g1part_kernel<<<G1BLKS + P2BLKS, 256, 0, stream>>>(
      x, W1, w1b2, h1, as1, ad1, esrc, edst, flag, bcur, bucketbuf);
  build_kernel<<<NBKT, 256, 0, stream>>>(bucketbuf, bb, rowptr, csr);
  agg1g2_kernel<<<6250, 256, 0, stream>>>(h1, as1, ad1, rowptr, csr, W2p,
                                          h2, as2, ad2);
  agg2_kernel<<<25000, 256, 0, stream>>>(h2, as2, ad2, rowptr, csr, b2,
                                         (float*)d_out);
}

// Round 20
// 236.825 us; speedup vs baseline: 1.0700x; 1.0213x over previous
//
#include <hip/hip_runtime.h>
#include <cstdint>
#include <cstddef>

#define NN 100000
#define NE 1600000
#define NH 8
#define NC 40
#define NBKT 391            // ceil(NN / 256)
#define CHUNK 4096
#define P2BLKS ((NE + CHUNK - 1) / CHUNK)
#define G1BLKS 1563         // gemm1 blocks
#define BCBLKS 256          // bucketcnt blocks fused into prep kernel

typedef _Float16 f16;
typedef f16 f16x2 __attribute__((ext_vector_type(2)));
typedef f16 f16x4 __attribute__((ext_vector_type(4)));
typedef f16 f16x8 __attribute__((ext_vector_type(8)));
typedef float f32x4 __attribute__((ext_vector_type(4)));

static __device__ __forceinline__ float leaky02(float x) {
  return x >= 0.f ? x : 0.2f * x;
}

static __device__ __forceinline__ int edge_at(const void* p, int is32, int i) {
  return is32 ? ((const int*)p)[i] : (int)((const long long*)p)[i];
}

// ---- prep + bucketcnt (259 blocks): b0 W2p, b1 w1b2, b2 detect->flag,
// b3..258 bucketcnt (per-block inline int-width detection, no flag dep).
__global__ __launch_bounds__(256) void prepbc_kernel(
    const float* __restrict__ W1, const float* __restrict__ att_src,
    const float* __restrict__ att_dst, const float* __restrict__ W2,
    const float* __restrict__ as2v, const float* __restrict__ ad2v,
    const int* __restrict__ esrc32, const void* __restrict__ edst,
    f16* __restrict__ W2p, float* __restrict__ w1b2,
    int* __restrict__ flag, int* __restrict__ gbucket) {
  __shared__ int lflag;
  __shared__ int hcnt[NBKT];
  const int t = threadIdx.x;
  if (blockIdx.x == 0) {
    for (int i = t; i < 8192; i += 256) {
      const int e = i & 7, lane = (i >> 3) & 63, tt = (i >> 9) & 3, s = (i >> 11) & 3;
      const int k = 32 * s + ((lane >> 4) << 3) + e;
      const int c = 16 * tt + (lane & 15);
      float v = 0.f;
      if (c < 40) {
        v = W2[k * 40 + c];
      } else if (c == 40 || c == 41) {
        const float* a = (c == 40) ? as2v : ad2v;
        float sacc = 0.f;
#pragma unroll 8
        for (int j = 0; j < 40; ++j) sacc += W2[k * 40 + j] * a[j];
        v = sacc;
      }
      W2p[i] = (f16)v;
    }
  } else if (blockIdx.x == 1) {
    const int k = t;
    if (k < 128) {
#pragma unroll
      for (int col = 0; col < 16; ++col) {
        const int h = col & 7;
        const float* av = (col < 8) ? att_src : att_dst;
        float v = 0.f;
#pragma unroll
        for (int f = 0; f < 16; ++f)
          v += W1[k * 128 + h * 16 + f] * av[h * 16 + f];
        w1b2[k * 16 + col] = v;
      }
    }
  } else if (blockIdx.x == 2) {
    if (t == 0) lflag = 0;
    __syncthreads();
    for (int i = t; i < 1024; i += 256)
      if (esrc32[2 * i + 1] != 0) atomicOr(&lflag, 1);
    __syncthreads();
    if (t == 0) *flag = lflag;
  } else {
    // ---- bucketcnt with per-block detection ----
    if (t == 0) lflag = 0;
    for (int i = t; i < NBKT; i += 256) hcnt[i] = 0;
    __syncthreads();
    int f = 0;
    const int* e32 = (const int*)edst;
    for (int i = t; i < 1024; i += 256) f |= (e32[2 * i + 1] != 0);
    if (__any(f)) { if ((t & 63) == 0) atomicOr(&lflag, 1); }
    __syncthreads();
    const int is32 = lflag;
    const int bid = blockIdx.x - 3;
    int i = bid * 256 + t;
    const int st = BCBLKS * 256;
    for (; i < NE; i += st) atomicAdd(&hcnt[edge_at(edst, is32, i) >> 8], 1);
    __syncthreads();
    for (int b = t; b < NBKT; b += 256)
      if (hcnt[b]) atomicAdd(&gbucket[b], hcnt[b]);
  }
}

// ------- fused: gemm1 (MFMA, blocks <G1BLKS) + partition (blocks >=G1BLKS) --
__global__ __launch_bounds__(256) void g1part_kernel(
    const float* __restrict__ x, const float* __restrict__ W1,
    const float* __restrict__ w1b2, f16* __restrict__ h1,
    float* __restrict__ as1, float* __restrict__ ad1,
    const void* __restrict__ esrc, const void* __restrict__ edst,
    const int* __restrict__ flag, int* __restrict__ bcur,
    unsigned int* __restrict__ bucketbuf) {
  __shared__ f16 wp[16384];    // [kt][ct][lane][e]
  __shared__ f16 wp2[2048];    // [kt][lane][e]
  __shared__ int h[NBKT];
  __shared__ int gb[NBKT];
  const int t = threadIdx.x;
  if (blockIdx.x >= G1BLKS) {
    // ---- partition part ----
    const int is32 = *flag;
    const int lo = (blockIdx.x - G1BLKS) * CHUNK;
    const int hi = min(lo + CHUNK, NE);
    for (int i = t; i < NBKT; i += 256) h[i] = 0;
    __syncthreads();
    for (int i = lo + t; i < hi; i += 256)
      atomicAdd(&h[edge_at(edst, is32, i) >> 8], 1);
    __syncthreads();
    for (int b = t; b < NBKT; b += 256)
      gb[b] = h[b] ? atomicAdd(&bcur[b], h[b]) : 0;
    __syncthreads();
    for (int i = t; i < NBKT; i += 256) h[i] = 0;   // reuse as local cursor
    __syncthreads();
    for (int i = lo + t; i < hi; i += 256) {
      int d = edge_at(edst, is32, i);
      int b = d >> 8;
      int s = atomicAdd(&h[b], 1);
      bucketbuf[gb[b] + s] =
          ((unsigned)(d & 255) << 17) | (unsigned)edge_at(esrc, is32, i);
    }
    return;
  }
  // ---- gemm1 part ----
  for (int i = t; i < 16384; i += 256) {
    const int e = i & 7, ln = (i >> 3) & 63, ct = (i >> 9) & 7, kt = i >> 12;
    const int k = kt * 32 + ((ln >> 4) << 3) + e;
    const int c = ct * 16 + (ln & 15);
    wp[i] = (f16)W1[k * 128 + c];
  }
  for (int i = t; i < 2048; i += 256) {
    const int e = i & 7, ln = (i >> 3) & 63, kt = i >> 9;
    const int k = kt * 32 + ((ln >> 4) << 3) + e;
    const int col = ln & 15;
    wp2[i] = (f16)w1b2[k * 16 + col];
  }
  __syncthreads();
  const int lane = t & 63;
  const int rsub = lane & 15, kg = lane >> 4;
  const int wid = (blockIdx.x * 256 + t) >> 6;
  if (wid >= NN / 16) return;
  const int row0 = wid * 16;
  const float* ap = x + (size_t)(row0 + rsub) * 128 + kg * 8;
  f16x8 a[4];
#pragma unroll
  for (int kt = 0; kt < 4; ++kt) {
    float4 v0 = *(const float4*)(ap + kt * 32);
    float4 v1 = *(const float4*)(ap + kt * 32 + 4);
    f16x8 av = { (f16)v0.x, (f16)v0.y, (f16)v0.z, (f16)v0.w,
                 (f16)v1.x, (f16)v1.y, (f16)v1.z, (f16)v1.w };
    a[kt] = av;
  }
  const f16x8* bp = (const f16x8*)wp;
  const f16x8* bp2 = (const f16x8*)wp2;
  const f32x4 z4 = { 0.f, 0.f, 0.f, 0.f };
  f32x4 acc[8];
#pragma unroll
  for (int ct = 0; ct < 8; ++ct) acc[ct] = z4;
  f32x4 acc2 = z4;
#pragma unroll
  for (int kt = 0; kt < 4; ++kt) {
#pragma unroll
    for (int ct = 0; ct < 8; ++ct)
      acc[ct] = __builtin_amdgcn_mfma_f32_16x16x32_f16(
          a[kt], bp[(kt * 8 + ct) * 64 + lane], acc[ct], 0, 0, 0);
    acc2 = __builtin_amdgcn_mfma_f32_16x16x32_f16(
        a[kt], bp2[kt * 64 + lane], acc2, 0, 0, 0);
  }
  const int r0 = row0 + kg * 4;
#pragma unroll
  for (int ct = 0; ct < 8; ++ct) {
#pragma unroll
    for (int r = 0; r < 4; ++r)
      h1[(size_t)(r0 + r) * 128 + ct * 16 + rsub] = (f16)acc[ct][r];
  }
#pragma unroll
  for (int r = 0; r < 4; ++r) {
    if (rsub < 8) as1[(r0 + r) * 8 + rsub] = acc2[r];
    else          ad1[(r0 + r) * 8 + rsub - 8] = acc2[r];
  }
}

// ---------------- CSR build: scan -> (partition fused above) -> build -------
__global__ __launch_bounds__(512) void bucketscan_kernel(
    const int* __restrict__ gbucket, int* __restrict__ bb,
    int* __restrict__ bcur) {
  __shared__ int wsum[8];
  const int t = threadIdx.x;
  const int lane = t & 63, w = t >> 6;
  int v = (t < NBKT) ? gbucket[t] : 0;
  int sc = v;
#pragma unroll
  for (int off = 1; off < 64; off <<= 1) {
    int o = __shfl_up(sc, off);
    if (lane >= off) sc += o;
  }
  if (lane == 63) wsum[w] = sc;
  __syncthreads();
  if (t < 8) {
    int ws = wsum[t];
#pragma unroll
    for (int off = 1; off < 8; off <<= 1) {
      int o = __shfl_up(ws, off);
      if (t >= off) ws += o;
    }
    wsum[t] = ws;
  }
  __syncthreads();
  if (w > 0) sc += wsum[w - 1];
  if (t < NBKT) {
    int ex = sc - v;
    bb[t] = ex;
    bcur[t] = ex;
  }
  if (t == NBKT - 1) bb[NBKT] = sc;   // == NE
}

__global__ __launch_bounds__(256) void build_kernel(
    const unsigned int* __restrict__ bucketbuf, const int* __restrict__ bb,
    int* __restrict__ rowptr, int* __restrict__ csr) {
  __shared__ int cnt[256];
  __shared__ int cur[256];
  __shared__ int wsum[4];
  const int k = blockIdx.x;
  const int t = threadIdx.x;
  const int node0 = k << 8;
  const int lo = bb[k], hi = bb[k + 1];
  cnt[t] = 0;
  __syncthreads();
  for (int i = lo + t; i < hi; i += 256)
    atomicAdd(&cnt[bucketbuf[i] >> 17], 1);
  __syncthreads();
  const int lane = t & 63, w = t >> 6;
  const int v = cnt[t];
  int sc = v;
#pragma unroll
  for (int off = 1; off < 64; off <<= 1) {
    int o = __shfl_up(sc, off);
    if (lane >= off) sc += o;
  }
  if (lane == 63) wsum[w] = sc;
  __syncthreads();
  if (t < 4) {
    int ws = wsum[t];
#pragma unroll
    for (int off = 1; off < 4; off <<= 1) {
      int o = __shfl_up(ws, off);
      if (t >= off) ws += o;
    }
    wsum[t] = ws;
  }
  __syncthreads();
  if (w > 0) sc += wsum[w - 1];
  const int ex = lo + sc - v;
  const int node = node0 + t;
  if (node < NN) rowptr[node] = ex;
  if (node == NN - 1) rowptr[NN] = NE;
  cur[t] = ex;
  __syncthreads();
  for (int i = lo + t; i < hi; i += 256) {
    unsigned e = bucketbuf[i];
    int pos = atomicAdd(&cur[e >> 17], 1);
    csr[pos] = (int)(e & 0x1FFFF);
  }
}

// --- layer-1 aggregate + softmax + ELU; g1 (f16) --- (round-14 exact)
// stats: lane = j*8+hd, first 4 batches cached in regs; PV: lane = q*16+part.
__global__ __launch_bounds__(256) void agg1_kernel(
    const f16* __restrict__ h1, const float* __restrict__ as1,
    const float* __restrict__ ad1, const int* __restrict__ rowptr,
    const int* __restrict__ csr, f16* __restrict__ g1) {
  const int wid = (blockIdx.x * 256 + threadIdx.x) >> 6;
  const int lane = threadIdx.x & 63;
  if (wid >= NN) return;
  const int lo = rowptr[wid], hi = rowptr[wid + 1];
  const int deg = hi - lo;
  const int j = lane >> 3, hd = lane & 7;
  const float advv = ad1[wid * 8 + hd];
  float lk0 = -3.4e38f, lk1 = -3.4e38f, lk2 = -3.4e38f, lk3 = -3.4e38f;
  int s0 = 0, s1 = 0, s2 = 0, s3 = 0;
  if (j < deg)      { s0 = csr[lo + j];      lk0 = leaky02(as1[(size_t)s0 * 8 + hd] + advv); }
  if (8 + j < deg)  { s1 = csr[lo + 8 + j];  lk1 = leaky02(as1[(size_t)s1 * 8 + hd] + advv); }
  if (16 + j < deg) { s2 = csr[lo + 16 + j]; lk2 = leaky02(as1[(size_t)s2 * 8 + hd] + advv); }
  if (24 + j < deg) { s3 = csr[lo + 24 + j]; lk3 = leaky02(as1[(size_t)s3 * 8 + hd] + advv); }
  float m = fmaxf(fmaxf(lk0, lk1), fmaxf(lk2, lk3));
  for (int base = 32; base < deg; base += 8) {   // rare tail
    int e = base + j;
    float xv = (e < deg) ? leaky02(as1[(size_t)csr[lo + e] * 8 + hd] + advv)
                         : -3.4e38f;
    m = fmaxf(m, xv);
  }
  m = fmaxf(m, __shfl_xor(m, 8));
  m = fmaxf(m, __shfl_xor(m, 16));
  m = fmaxf(m, __shfl_xor(m, 32));
  const int q = lane >> 4;          // PV edge sub-slot (0..3)
  const int part = lane & 15;       // 8-feature block
  float sum = 0.f;
  float acc[8];
#pragma unroll
  for (int i = 0; i < 8; ++i) acc[i] = 0.f;
  for (int base = 0; base < deg; base += 8) {
    int e = base + j;
    float p = 0.f;
    int s = 0;
    if (base == 0)       { s = s0; if (e < deg) p = __expf(lk0 - m); }
    else if (base == 8)  { s = s1; if (e < deg) p = __expf(lk1 - m); }
    else if (base == 16) { s = s2; if (e < deg) p = __expf(lk2 - m); }
    else if (base == 24) { s = s3; if (e < deg) p = __expf(lk3 - m); }
    else if (e < deg) {
      s = csr[lo + e];
      p = __expf(leaky02(as1[(size_t)s * 8 + hd] + advv) - m);
    }
    sum += p;
    int sja = __shfl(s, q * 8);
    float pja = __shfl(p, q * 8 + (part >> 1));
    int sjb = __shfl(s, (4 + q) * 8);
    float pjb = __shfl(p, (4 + q) * 8 + (part >> 1));
    f16x8 hva = *(const f16x8*)(h1 + (size_t)sja * 128 + part * 8);
    f16x8 hvb = *(const f16x8*)(h1 + (size_t)sjb * 128 + part * 8);
#pragma unroll
    for (int i = 0; i < 8; ++i) acc[i] += pja * (float)hva[i];
#pragma unroll
    for (int i = 0; i < 8; ++i) acc[i] += pjb * (float)hvb[i];
  }
  sum += __shfl_xor(sum, 8);
  sum += __shfl_xor(sum, 16);
  sum += __shfl_xor(sum, 32);
#pragma unroll
  for (int i = 0; i < 8; ++i) {
    acc[i] += __shfl_xor(acc[i], 16);
    acc[i] += __shfl_xor(acc[i], 32);
  }
  float sden = __shfl(sum, part >> 1);
  float inv = 1.f / fmaxf(sden, 1e-16f);
  if (lane < 16) {
    f16x8 ov;
#pragma unroll
    for (int i = 0; i < 8; ++i) {
      float v = acc[i] * inv;
      v = v > 0.f ? v : (__expf(v) - 1.f);
      ov[i] = (f16)v;
    }
    *(f16x8*)(g1 + (size_t)wid * 128 + part * 8) = ov;
  }
}

// ------- layer-2 projection via MFMA: h2 = g1 @ W2 (40 cols) + logits -------
__global__ __launch_bounds__(256) void gemm2_kernel(
    const f16* __restrict__ g1, const f16* __restrict__ W2p,
    f16* __restrict__ h2, float* __restrict__ as2, float* __restrict__ ad2) {
  const int lane = threadIdx.x & 63;
  const int wid = (blockIdx.x * 256 + threadIdx.x) >> 6;
  if (wid >= NN / 16) return;
  const int row0 = wid * 16;
  const int rsub = lane & 15;
  const int kg = lane >> 4;
  const f16* ap = g1 + (size_t)(row0 + rsub) * 128 + kg * 8;
  f16x8 a0 = *(const f16x8*)(ap);
  f16x8 a1 = *(const f16x8*)(ap + 32);
  f16x8 a2 = *(const f16x8*)(ap + 64);
  f16x8 a3 = *(const f16x8*)(ap + 96);
  const f16x8* bp = (const f16x8*)W2p;
  f32x4 acc[3];
  const f32x4 z4 = { 0.f, 0.f, 0.f, 0.f };
#pragma unroll
  for (int t = 0; t < 3; ++t) acc[t] = z4;
#pragma unroll
  for (int t = 0; t < 3; ++t) {   // t=3 tile is all-zero B -> dropped
    acc[t] = __builtin_amdgcn_mfma_f32_16x16x32_f16(a0, bp[(0 * 4 + t) * 64 + lane], acc[t], 0, 0, 0);
    acc[t] = __builtin_amdgcn_mfma_f32_16x16x32_f16(a1, bp[(1 * 4 + t) * 64 + lane], acc[t], 0, 0, 0);
    acc[t] = __builtin_amdgcn_mfma_f32_16x16x32_f16(a2, bp[(2 * 4 + t) * 64 + lane], acc[t], 0, 0, 0);
    acc[t] = __builtin_amdgcn_mfma_f32_16x16x32_f16(a3, bp[(3 * 4 + t) * 64 + lane], acc[t], 0, 0, 0);
  }
  const int r0 = row0 + kg * 4;
#pragma unroll
  for (int t = 0; t < 3; ++t) {
    const int col = t * 16 + rsub;
    if (col < 40) {
#pragma unroll
      for (int r = 0; r < 4; ++r)
        h2[(size_t)(r0 + r) * 40 + col] = (f16)acc[t][r];
    }
  }
  if (rsub == 8) {          // col 40: src logits
#pragma unroll
    for (int r = 0; r < 4; ++r) as2[r0 + r] = acc[2][r];
  } else if (rsub == 9) {   // col 41: dst logits
#pragma unroll
    for (int r = 0; r < 4; ++r) ad2[r0 + r] = acc[2][r];
  }
}

// ---------------- layer-2 aggregate + softmax -> d_out ----------------
__global__ __launch_bounds__(256) void agg2_kernel(
    const f16* __restrict__ h2, const float* __restrict__ as2,
    const float* __restrict__ ad2, const int* __restrict__ rowptr,
    const int* __restrict__ csr, const float* __restrict__ b2,
    float* __restrict__ out) {
  const int wid = (blockIdx.x * 256 + threadIdx.x) >> 6;
  const int lane = threadIdx.x & 63;
  if (wid >= NN) return;
  const int lo = rowptr[wid], hi = rowptr[wid + 1];
  const int deg = hi - lo;
  const float advv = ad2[wid];
  float lkc = -3.4e38f;
  int sc = 0;
  if (lane < deg) {
    sc = csr[lo + lane];
    lkc = leaky02(as2[sc] + advv);
  }
  float m = lkc;
  for (int base = 64; base < deg; base += 64) {   // rare tail
    int e = base + lane;
    float xv = (e < deg) ? leaky02(as2[csr[lo + e]] + advv) : -3.4e38f;
    m = fmaxf(m, xv);
  }
#pragma unroll
  for (int off = 32; off >= 1; off >>= 1) m = fmaxf(m, __shfl_xor(m, off));
  const int j8 = lane >> 3, part8 = lane & 7;
  const bool pvon = part8 < 5;
  float sum = 0.f;
  float acc[8];
#pragma unroll
  for (int i = 0; i < 8; ++i) acc[i] = 0.f;
  for (int base = 0; base < deg; base += 64) {
    int e = base + lane;
    float p = 0.f;
    int s = 0;
    if (base == 0) {
      s = sc;
      if (lane < deg) p = __expf(lkc - m);
    } else if (e < deg) {
      s = csr[lo + e];
      p = __expf(leaky02(as2[s] + advv) - m);
    }
    sum += p;
    const int ng = (min(64, deg - base) + 7) >> 3;
    int g = 0;
    for (; g + 1 < ng; g += 2) {
      int sl1 = g * 8 + j8, sl2 = (g + 1) * 8 + j8;
      int sj1 = __shfl(s, sl1);
      float pj1 = __shfl(p, sl1);
      int sj2 = __shfl(s, sl2);
      float pj2 = __shfl(p, sl2);
      if (pvon) {
        f16x8 hv1 = *(const f16x8*)(h2 + (size_t)sj1 * 40 + part8 * 8);
        f16x8 hv2 = *(const f16x8*)(h2 + (size_t)sj2 * 40 + part8 * 8);
#pragma unroll
        for (int i = 0; i < 8; ++i) acc[i] += pj1 * (float)hv1[i];
#pragma unroll
        for (int i = 0; i < 8; ++i) acc[i] += pj2 * (float)hv2[i];
      }
    }
    if (g < ng) {
      int sl = g * 8 + j8;
      int sj = __shfl(s, sl);
      float pj = __shfl(p, sl);
      if (pvon) {
        f16x8 hv = *(const f16x8*)(h2 + (size_t)sj * 40 + part8 * 8);
#pragma unroll
        for (int i = 0; i < 8; ++i) acc[i] += pj * (float)hv[i];
      }
    }
  }
#pragma unroll
  for (int off = 32; off >= 1; off >>= 1) sum += __shfl_xor(sum, off);
#pragma unroll
  for (int i = 0; i < 8; ++i) {
    acc[i] += __shfl_xor(acc[i], 8);
    acc[i] += __shfl_xor(acc[i], 16);
    acc[i] += __shfl_xor(acc[i], 32);
  }
  const float inv = 1.f / fmaxf(sum, 1e-16f);
  if (lane < 5) {   // j8 == 0, part8 == lane -> cols lane*8 .. lane*8+7
    float4 b0 = *(const float4*)(b2 + lane * 8);
    float4 b1 = *(const float4*)(b2 + lane * 8 + 4);
    float4 v0 = { acc[0] * inv + b0.x, acc[1] * inv + b0.y,
                  acc[2] * inv + b0.z, acc[3] * inv + b0.w };
    float4 v1 = { acc[4] * inv + b1.x, acc[5] * inv + b1.y,
                  acc[6] * inv + b1.z, acc[7] * inv + b1.w };
    *(float4*)(out + (size_t)wid * 40 + lane * 8) = v0;
    *(float4*)(out + (size_t)wid * 40 + lane * 8 + 4) = v1;
  }
}

extern "C" void kernel_launch(void* const* d_in, const int* in_sizes, int n_in,
                              void* d_out, int out_size, void* d_ws, size_t ws_size,
                              hipStream_t stream) {
  (void)in_sizes; (void)n_in; (void)out_size; (void)ws_size;
  const float* x = (const float*)d_in[0];
  const void* esrc = d_in[1];
  const void* edst = d_in[2];
  const float* W1 = (const float*)d_in[3];
  const float* att_s1 = (const float*)d_in[4];
  const float* att_d1 = (const float*)d_in[5];
  const float* W2 = (const float*)d_in[7];
  const float* att_s2 = (const float*)d_in[8];
  const float* att_d2 = (const float*)d_in[9];
  const float* b2 = (const float*)d_in[10];

  char* p = (char*)d_ws;
  auto alloc = [&](size_t bytes) {
    char* q = p;
    p += (bytes + 255) & ~(size_t)255;
    return q;
  };
  f16* h1 = (f16*)alloc((size_t)NN * 128 * 2);
  f16* g1 = (f16*)alloc((size_t)NN * 128 * 2);
  f16* h2 = (f16*)alloc((size_t)NN * 40 * 2);
  float* as1 = (float*)alloc((size_t)NN * 8 * 4);
  float* ad1 = (float*)alloc((size_t)NN * 8 * 4);
  float* as2 = (float*)alloc((size_t)NN * 4);
  float* ad2 = (float*)alloc((size_t)NN * 4);
  f16* W2p = (f16*)alloc((size_t)8192 * 2);
  float* w1b2 = (float*)alloc((size_t)128 * 16 * 4);
  int* rowptr = (int*)alloc((size_t)(NN + 1) * 4);
  int* csr = (int*)alloc((size_t)NE * 4);
  unsigned int* bucketbuf = (unsigned int*)alloc((size_t)NE * 4);
  int* gbucket = (int*)alloc((size_t)NBKT * 4);
  int* bb = (int*)alloc((size_t)(NBKT + 1) * 4);
  int* bcur = (int*)alloc((size_t)NBKT * 4);
  int* flag = (int*)alloc(256);

  hipMemsetAsync(gbucket, 0, (size_t)NBKT * 4, stream);
  prepbc_kernel<<<3 + BCBLKS, 256, 0, stream>>>(
      W1, att_s1, att_d1, W2, att_s2, att_d2, (const int*)esrc, edst,
      W2p, w1b2, flag, gbucket);
  bucketscan_kernel<<<1, 512, 0, stream>>>(gbucket, bb, bcur);
  g1part_kernel<<<G1BLKS + P2BLKS, 256, 0, stream>>>(
      x, W1, w1b2, h1, as1, ad1, esrc, edst, flag, bcur, bucketbuf);
  build_kernel<<<NBKT, 256, 0, stream>>>(bucketbuf, bb, rowptr, csr);
  agg1_kernel<<<25000, 256, 0, stream>>>(h1, as1, ad1, rowptr, csr, g1);
  gemm2_kernel<<<1563, 256, 0, stream>>>(g1, W2p, h2, as2, ad2);
  agg2_kernel<<<25000, 256, 0, stream>>>(h2, as2, ad2, rowptr, csr, b2,
                                         (float*)d_out);
}